// Round 19
// baseline (488.456 us; speedup 1.0000x reference)
//
#include <hip/hip_runtime.h>
#include <math.h>

#define S 16384      // 128*128 spatial
#define HW 128

typedef __attribute__((ext_vector_type(8))) short short8;
typedef __attribute__((ext_vector_type(4))) float f32x4;

__device__ __forceinline__ float mishf(float t) {
    float sp = (t > 20.0f) ? t : __logf(1.0f + __expf(t));
    float e2 = __expf(-2.0f * sp);
    return t * (1.0f - e2) * __builtin_amdgcn_rcpf(1.0f + e2);
}
__device__ __forceinline__ short f2bf(float f) {   // RNE f32 -> bf16 bits
    unsigned u = __float_as_uint(f);
    unsigned r = (u + 0x7FFFu + ((u >> 16) & 1u)) >> 16;
    return (short)r;
}
__device__ __forceinline__ float bf2f(short s) {
    unsigned u = ((unsigned)(unsigned short)s) << 16;
    return __uint_as_float(u);
}
__device__ __forceinline__ unsigned packhl(float v) {  // lo16=hi part, hi16=lo part
    short h = f2bf(v);
    short l = f2bf(v - bf2f(h));
    return (unsigned)(unsigned short)h | ((unsigned)(unsigned short)l << 16);
}
__device__ __forceinline__ void gl_lds16(const void* g, void* l) {
    __builtin_amdgcn_global_load_lds(
        (const __attribute__((address_space(1))) unsigned int*)g,
        (__attribute__((address_space(3))) unsigned int*)l, 16, 0, 0);
}
// swizzled LDS fragment read for [px][256B] rows
__device__ __forceinline__ short8 lds_frag(const char* base, int a) {
    int p = a ^ (((a >> 8) & 7) << 4);
    return *(const short8*)(base + p);
}
// swizzled LDS fragment read for [px][128B] rows
__device__ __forceinline__ short8 lds_frag128(const char* base, int a) {
    int p = a ^ (((a >> 7) & 7) << 4);
    return *(const short8*)(base + p);
}
__device__ __forceinline__ int swz128(int a) { return a ^ (((a >> 7) & 7) << 4); }
#define MFMA(a, b, c) __builtin_amdgcn_mfma_f32_16x16x32_bf16(a, b, c, 0, 0, 0)

// ---------------- prep: bf16 weights (2-term scheme) + zero t0p borders ----------------
__global__ void prep_kernel(const float* __restrict__ wq, const float* __restrict__ wk, const float* __restrict__ wv,
                            const float* __restrict__ bnq_s, const float* __restrict__ bnq_b,
                            const float* __restrict__ bnk_s, const float* __restrict__ bnk_b,
                            const float* __restrict__ bnv_s, const float* __restrict__ bnv_b,
                            const float* __restrict__ wpw, const float* __restrict__ wproj,
                            const float* __restrict__ wrow, const float* __restrict__ wcol,
                            const float* __restrict__ fc1_w, const float* __restrict__ wdw,
                            short* __restrict__ wqkv_h,
                            float* __restrict__ sqkv, float* __restrict__ bqkv,
                            short* __restrict__ wpw_h,
                            short* __restrict__ wproj_h,
                            float* __restrict__ wrowT, float* __restrict__ wcolT,
                            short* __restrict__ wch,
                            float* __restrict__ wdwT,
                            short* __restrict__ t0ph, short* __restrict__ t0pl) {
    int tid = blockIdx.x * 256 + threadIdx.x;
    if (tid < 256 * 128) {            // wqkv [oc 256][ic 128] bf16
        int oc = tid >> 7, ic = tid & 127;
        float w = (oc < 64) ? wq[oc * 128 + ic]
                : (oc < 128) ? wk[(oc - 64) * 128 + ic]
                : wv[(oc - 128) * 128 + ic];
        wqkv_h[tid] = f2bf(w);
    }
    if (tid < 256) {
        sqkv[tid] = (tid < 64) ? bnq_s[tid] : (tid < 128) ? bnk_s[tid - 64] : bnv_s[tid - 128];
        bqkv[tid] = (tid < 64) ? bnq_b[tid] : (tid < 128) ? bnk_b[tid - 64] : bnv_b[tid - 128];
    }
    if (tid < 128 * 256) {            // wpw [oc 128][ic 256] bf16
        wpw_h[tid] = f2bf(wpw[tid]);
    }
    if (tid < 128 * 128) {
        wproj_h[tid] = f2bf(wproj[tid]);   // [oc][ic]
        int ic = tid >> 7, oc = tid & 127;
        wrowT[tid] = wrow[oc * 128 + ic];
        wcolT[tid] = wcol[oc * 128 + ic];
    }
    if (tid < 9 * 128 * 128) {        // conv3x3 [tap][oc][ic] bf16
        int tap = tid >> 14;
        int oc = (tid >> 7) & 127;
        int ic = tid & 127;
        wch[tid] = f2bf(fc1_w[(oc * 128 + ic) * 9 + tap]);
    }
    if (tid < 9 * 256) {              // depthwise [tap][c]
        int tap = tid / 256, c = tid % 256;
        wdwT[tap * 256 + c] = wdw[c * 9 + tap];
    }
    if (tid < 132096) {               // border zero
        int bb = tid / 16512;
        int rem = tid - bb * 16512;
        int part = rem / 8256;
        int e = rem - part * 8256;
        short* p = part ? t0pl : t0ph;
        size_t ib = (size_t)bb * 130 * 130 * 128;
        short8 z = (short8){0, 0, 0, 0, 0, 0, 0, 0};
        if (e < 4160) {
            int row = (e < 2080) ? 0 : 129;
            int off = (e % 2080) * 8;
            *(short8*)(p + ib + (size_t)row * 130 * 128 + off) = z;
        } else {
            int e2 = e - 4160;
            int row = 1 + (e2 >> 5);
            int side = (e2 >> 4) & 1;
            int off = (e2 & 15) * 8;
            *(short8*)(p + ib + ((size_t)row * 130 + (side ? 129 : 0)) * 128 + off) = z;
        }
    }
}

// ---------------- pool (avg+max) + BN + Mish -> padded NHWC split bf16 ----------------
__global__ __launch_bounds__(256) void pool_kernel(const float* __restrict__ x,
                                                   const float* __restrict__ s1, const float* __restrict__ b1,
                                                   short* __restrict__ t0ph, short* __restrict__ t0pl) {
    __shared__ unsigned ot[64][132];
    int bx = blockIdx.x;               // 0..255
    int b = blockIdx.y;
    int h = bx >> 1, wh = bx & 1;
    int t = threadIdx.x;
    int wp = t & 31;                   // w-pair index (2 outputs each)
    int c8 = t >> 5;                   // 0..7
    int w0 = wh * 64 + wp * 2;
    for (int cs = 0; cs < 8; ++cs) {
        int c = cs * 8 + c8;           // 0..63
        const float* xp = x + (size_t)(b * 64 + c) * 65536;
        float vs[3][5], vm[3][5];
        #pragma unroll
        for (int kh = 0; kh < 3; ++kh) {
            int ih = 2 * h + kh - 1;
            bool hok = (unsigned)ih < 256u;
            #pragma unroll
            for (int j = 0; j < 5; ++j) {
                int iw = 2 * w0 - 1 + j;
                bool ok = hok && (unsigned)iw < 256u;
                float v = ok ? xp[ih * 256 + iw] : 0.f;
                vs[kh][j] = ok ? v : 0.f;
                vm[kh][j] = ok ? v : -INFINITY;
            }
        }
        #pragma unroll
        for (int o = 0; o < 2; ++o) {
            float sum = 0.f, mx = -INFINITY;
            #pragma unroll
            for (int kh = 0; kh < 3; ++kh)
                #pragma unroll
                for (int kw = 0; kw < 3; ++kw) {
                    sum += vs[kh][kw + 2 * o];
                    mx = fmaxf(mx, vm[kh][kw + 2 * o]);
                }
            float ta = mishf((sum * (1.f / 9.f)) * s1[c] + b1[c]);
            float tm = mishf(mx * s1[64 + c] + b1[64 + c]);
            ot[wp * 2 + o][c] = packhl(ta);
            ot[wp * 2 + o][64 + c] = packhl(tm);
        }
    }
    __syncthreads();
    size_t rowbase = ((size_t)(b * 130 + h + 1) * 130 + 1 + wh * 64) * 128;
    short* oph = t0ph + rowbase;
    short* opl = t0pl + rowbase;
    for (int idx = t; idx < 64 * 16; idx += 256) {
        int wloc = idx >> 4, co = idx & 15;
        short8 hv, lv;
        #pragma unroll
        for (int j = 0; j < 8; ++j) {
            unsigned u = ot[wloc][co * 8 + j];
            hv[j] = (short)(u & 0xFFFFu);
            lv[j] = (short)(u >> 16);
        }
        *(short8*)(oph + wloc * 128 + co * 8) = hv;
        *(short8*)(opl + wloc * 128 + co * 8) = lv;
    }
}

// ---------------- FUSED conv3x3 + qkv 1x1, 512 threads / 8 waves, 2-term split ----------------
__global__ __launch_bounds__(512) void convqkv_mfma(const short* __restrict__ t0ph,
                                                    const short* __restrict__ t0pl,
                                                    const short* __restrict__ wch,
                                                    const float* __restrict__ fb,
                                                    const short* __restrict__ wqkv_h,
                                                    const float* __restrict__ sc, const float* __restrict__ bi,
                                                    float* __restrict__ qf, float* __restrict__ rowmean) {
    __shared__ char sm[69632];          // staging 2x33792; reused as A-pack 2x[128][132]; rsum [2][256] at 67584
    char* smh = sm;
    char* sml = sm + 33792;
    float* rsum = (float*)(sm + 67584);
    int flat = blockIdx.x;              // 1024
    int b = flat & 7;                   // XCD-affine
    int h = flat >> 3;
    int tid = threadIdx.x, lane = tid & 63, wid = tid >> 6;
    int l15 = lane & 15, l4 = lane >> 4;
    int wrc = wid >> 2;                 // conv px half
    int wcc = wid & 3;                  // conv oc quarter (32 oc)
    int spbc = wrc * 64 + l15;
    int ocbc = wcc * 32 + l15;
    f32x4 acc[4][2];
    #pragma unroll
    for (int m = 0; m < 4; ++m)
        #pragma unroll
        for (int n = 0; n < 2; ++n) acc[m][n] = (f32x4){0.f, 0.f, 0.f, 0.f};
    for (int kh = 0; kh < 3; ++kh) {
        __syncthreads();
        const char* gh = (const char*)(t0ph + ((size_t)(b * 130 + h + kh) * 130) * 128);
        const char* gl = (const char*)(t0pl + ((size_t)(b * 130 + h + kh) * 130) * 128);
        #pragma unroll
        for (int it = 0; it < 5; ++it) {
            int idx = it * 512 + tid;           // 2080 x 16B per plane
            if (idx < 2080) {
                int dl = idx * 16;
                int srcoff = dl ^ (((dl >> 8) & 7) << 4);
                gl_lds16(gh + srcoff, smh + dl);
                gl_lds16(gl + srcoff, sml + dl);
            }
        }
        __syncthreads();
        #pragma unroll
        for (int kw = 0; kw < 3; ++kw) {
            const short* wbh = wch + (size_t)(kh * 3 + kw) * 16384;
            #pragma unroll
            for (int ks = 0; ks < 4; ++ks) {
                int kb = ks * 64 + l4 * 16;
                int kws = ks * 32 + l4 * 8;
                short8 ah[4], bh[2];
                #pragma unroll
                for (int m = 0; m < 4; ++m)
                    ah[m] = lds_frag(smh, ((spbc + m * 16 + kw) << 8) + kb);
                #pragma unroll
                for (int n = 0; n < 2; ++n)
                    bh[n] = *(const short8*)(wbh + (ocbc + n * 16) * 128 + kws);
                #pragma unroll
                for (int m = 0; m < 4; ++m)
                    #pragma unroll
                    for (int n = 0; n < 2; ++n)
                        acc[m][n] = MFMA(ah[m], bh[n], acc[m][n]);
                short8 al[4];
                #pragma unroll
                for (int m = 0; m < 4; ++m)
                    al[m] = lds_frag(sml, ((spbc + m * 16 + kw) << 8) + kb);
                #pragma unroll
                for (int m = 0; m < 4; ++m)
                    #pragma unroll
                    for (int n = 0; n < 2; ++n)
                        acc[m][n] = MFMA(al[m], bh[n], acc[m][n]);
                // 2-term: a_h*w_l dropped (weights bf16)
            }
        }
    }
    // pack conv output (y row) + bias into split-bf16 A tile in LDS
    float fbv[2];
    #pragma unroll
    for (int n = 0; n < 2; ++n) fbv[n] = fb[wcc * 32 + n * 16 + l15];
    rsum[tid] = 0.f;                    // 512 entries
    __syncthreads();
    short* ahi = (short*)sm;            // [128][132]
    short* alo = (short*)(sm + 33792);  // [128][132]
    #pragma unroll
    for (int m = 0; m < 4; ++m)
        #pragma unroll
        for (int n = 0; n < 2; ++n)
            #pragma unroll
            for (int r = 0; r < 4; ++r) {
                int px = wrc * 64 + m * 16 + l4 * 4 + r;
                int ocl = wcc * 32 + n * 16 + l15;
                unsigned u = packhl(acc[m][n][r] + fbv[n]);
                ahi[px * 132 + ocl] = (short)(u & 0xFFFFu);
                alo[px * 132 + ocl] = (short)(u >> 16);
            }
    __syncthreads();
    // qkv GEMM: A[128px][128ic] (LDS) x B[256oc][128ic], 8 waves, 2-term
    int spbq = wrc * 64 + l15;          // px half (reuse wrc)
    int ocbq = wcc * 64 + l15;          // oc quarter of 256 (64 oc)
    f32x4 aq[4][4];
    #pragma unroll
    for (int m = 0; m < 4; ++m)
        #pragma unroll
        for (int n = 0; n < 4; ++n) aq[m][n] = (f32x4){0.f, 0.f, 0.f, 0.f};
    #pragma unroll
    for (int ks = 0; ks < 4; ++ks) {
        int k0 = ks * 32 + l4 * 8;
        short8 ah[4], bh[4];
        #pragma unroll
        for (int m = 0; m < 4; ++m) ah[m] = *(const short8*)(ahi + (spbq + m * 16) * 132 + k0);
        #pragma unroll
        for (int n = 0; n < 4; ++n) bh[n] = *(const short8*)(wqkv_h + (size_t)(ocbq + n * 16) * 128 + k0);
        #pragma unroll
        for (int m = 0; m < 4; ++m)
            #pragma unroll
            for (int n = 0; n < 4; ++n) aq[m][n] = MFMA(ah[m], bh[n], aq[m][n]);
        short8 al[4];
        #pragma unroll
        for (int m = 0; m < 4; ++m) al[m] = *(const short8*)(alo + (spbq + m * 16) * 132 + k0);
        #pragma unroll
        for (int m = 0; m < 4; ++m)
            #pragma unroll
            for (int n = 0; n < 4; ++n) aq[m][n] = MFMA(al[m], bh[n], aq[m][n]);
        // 2-term: a_h*w_l dropped
    }
    // rowsum partials (raw acc; scale/bias at final store)
    #pragma unroll
    for (int n = 0; n < 4; ++n) {
        float v = 0.f;
        #pragma unroll
        for (int m = 0; m < 4; ++m)
            #pragma unroll
            for (int r = 0; r < 4; ++r) v += aq[m][n][r];
        v += __shfl_xor(v, 16);
        v += __shfl_xor(v, 32);
        if (l4 == 0) rsum[wrc * 256 + wcc * 64 + n * 16 + l15] = v;
    }
    // BN + direct f32 store
    float s4[4], b4[4];
    #pragma unroll
    for (int n = 0; n < 4; ++n) {
        s4[n] = sc[wcc * 64 + n * 16 + l15];
        b4[n] = bi[wcc * 64 + n * 16 + l15];
    }
    float* rowout = qf + ((size_t)(b * 128 + h) * 128) * 256;
    #pragma unroll
    for (int m = 0; m < 4; ++m)
        #pragma unroll
        for (int n = 0; n < 4; ++n)
            #pragma unroll
            for (int r = 0; r < 4; ++r) {
                int px = wrc * 64 + m * 16 + l4 * 4 + r;
                int oc = wcc * 64 + n * 16 + l15;
                rowout[px * 256 + oc] = aq[m][n][r] * s4[n] + b4[n];
            }
    __syncthreads();
    if (tid < 256)
        rowmean[((size_t)b * 256 + tid) * 128 + h] =
            (rsum[tid] + rsum[256 + tid]) * sc[tid] * (1.f / 128.f) + bi[tid];
}

// ---------------- colmean: mean over h of qkv f32 NHWC ----------------
__global__ __launch_bounds__(256) void colmean_kernel(const float* __restrict__ qf,
                                                      float* __restrict__ colmean) {
    __shared__ float red[8][256];
    int blk = blockIdx.x;                 // 1024
    int b = blk & 7, w = blk >> 3;        // XCD-affine
    int tid = threadIdx.x;
    int c8g = tid & 31;                   // channel group of 8
    int hs = tid >> 5;                    // 8 h-slices of 16
    float a8[8];
    #pragma unroll
    for (int k = 0; k < 8; ++k) a8[k] = 0.f;
    for (int j = 0; j < 16; ++j) {
        int h = hs * 16 + j;
        const float* p = qf + ((size_t)((b * 128 + h) * 128 + w)) * 256 + c8g * 8;
        float4 v0 = *(const float4*)p;
        float4 v1 = *(const float4*)(p + 4);
        a8[0] += v0.x; a8[1] += v0.y; a8[2] += v0.z; a8[3] += v0.w;
        a8[4] += v1.x; a8[5] += v1.y; a8[6] += v1.z; a8[7] += v1.w;
    }
    #pragma unroll
    for (int k = 0; k < 8; ++k) red[hs][c8g * 8 + k] = a8[k];
    __syncthreads();
    int c = tid;
    float s = 0.f;
    #pragma unroll
    for (int q = 0; q < 8; ++q) s += red[q][c];
    colmean[((size_t)b * 256 + c) * 128 + w] = s * (1.f / 128.f);
}

// ---------------- fused depthwise 3x3 + BN + ReLU + pointwise 256->128 MFMA + BN ----------------
// dw phase: joint 3x4 window loaded once per 4-ch half, both outputs from registers
// (24 float4 loads vs 36 per thread per chunk).
__global__ __launch_bounds__(512) void dwpw_mfma(const float* __restrict__ qf,
                                                 const float* __restrict__ wdwT,
                                                 const float* __restrict__ ds, const float* __restrict__ db,
                                                 const short* __restrict__ wpw_h,
                                                 const float* __restrict__ sc, const float* __restrict__ bi,
                                                 float* __restrict__ qb) {
    __shared__ char sm[32768];
    char* smh = sm;           // dw out hi, [128w][128B] swizzled (64 c chunk)
    char* sml = sm + 16384;   // dw out lo
    int flat = blockIdx.x;
    int b = flat & 7, h = flat >> 3;
    int tid = threadIdx.x, lane = tid & 63, wid = tid >> 6;
    int wr = wid >> 2, wc = wid & 3;     // px half / oc quarter (32 oc)
    int l15 = lane & 15, l4 = lane >> 4;
    int spb = wr * 64 + l15;
    int ocb = wc * 32 + l15;
    int wl0 = (tid >> 3) * 2;            // local w base (2 outputs)
    int c8t = tid & 7;                   // c8 group within 64-c chunk
    f32x4 acc[4][2];
    #pragma unroll
    for (int m = 0; m < 4; ++m)
        #pragma unroll
        for (int n = 0; n < 2; ++n) acc[m][n] = (f32x4){0.f, 0.f, 0.f, 0.f};

    #pragma unroll 1
    for (int kc = 0; kc < 4; ++kc) {
        __syncthreads();      // previous chunk's MFMA reads done
        int cbase = kc * 64 + c8t * 8;
        float a0[8], a1[8];
        #pragma unroll
        for (int k = 0; k < 8; ++k) { a0[k] = 0.f; a1[k] = 0.f; }
        #pragma unroll
        for (int cc = 0; cc < 2; ++cc) {
            float4 r[3][4];
            #pragma unroll
            for (int kh = 0; kh < 3; ++kh) {
                int ih = h + kh - 1;
                bool hok = (unsigned)ih < 128u;
                #pragma unroll
                for (int j = 0; j < 4; ++j) {
                    int iw = wl0 - 1 + j;
                    bool ok = hok && (unsigned)iw < 128u;
                    r[kh][j] = ok ? *(const float4*)(qf + ((size_t)((b * 128 + ih) * 128 + iw)) * 256 + cbase + cc * 4)
                                  : make_float4(0.f, 0.f, 0.f, 0.f);
                }
            }
            #pragma unroll
            for (int kh = 0; kh < 3; ++kh)
                #pragma unroll
                for (int kw = 0; kw < 3; ++kw) {
                    const float* wp = wdwT + (kh * 3 + kw) * 256 + cbase + cc * 4;
                    float4 v0 = r[kh][kw];
                    float4 v1 = r[kh][kw + 1];
                    a0[cc * 4 + 0] += wp[0] * v0.x; a1[cc * 4 + 0] += wp[0] * v1.x;
                    a0[cc * 4 + 1] += wp[1] * v0.y; a1[cc * 4 + 1] += wp[1] * v1.y;
                    a0[cc * 4 + 2] += wp[2] * v0.z; a1[cc * 4 + 2] += wp[2] * v1.z;
                    a0[cc * 4 + 3] += wp[3] * v0.w; a1[cc * 4 + 3] += wp[3] * v1.w;
                }
        }
        short8 hv0, lv0, hv1, lv1;
        #pragma unroll
        for (int k = 0; k < 8; ++k) {
            float v0 = fmaxf(a0[k] * ds[cbase + k] + db[cbase + k], 0.f);
            float v1 = fmaxf(a1[k] * ds[cbase + k] + db[cbase + k], 0.f);
            unsigned u0 = packhl(v0);
            unsigned u1 = packhl(v1);
            hv0[k] = (short)(u0 & 0xFFFFu); lv0[k] = (short)(u0 >> 16);
            hv1[k] = (short)(u1 & 0xFFFFu); lv1[k] = (short)(u1 >> 16);
        }
        int a0a = swz128(wl0 * 128 + c8t * 16);
        int a1a = swz128((wl0 + 1) * 128 + c8t * 16);
        *(short8*)(smh + a0a) = hv0;
        *(short8*)(sml + a0a) = lv0;
        *(short8*)(smh + a1a) = hv1;
        *(short8*)(sml + a1a) = lv1;
        __syncthreads();
        #pragma unroll
        for (int ks = 0; ks < 2; ++ks) {
            int kb = ks * 64 + l4 * 16;               // byte offset in 128B row
            int kws = kc * 64 + ks * 32 + l4 * 8;     // weight short offset (ic)
            short8 ah[4], bh[2];
            #pragma unroll
            for (int m = 0; m < 4; ++m) ah[m] = lds_frag128(smh, (spb + m * 16) * 128 + kb);
            #pragma unroll
            for (int n = 0; n < 2; ++n) bh[n] = *(const short8*)(wpw_h + (ocb + n * 16) * 256 + kws);
            #pragma unroll
            for (int m = 0; m < 4; ++m)
                #pragma unroll
                for (int n = 0; n < 2; ++n) acc[m][n] = MFMA(ah[m], bh[n], acc[m][n]);
            short8 al[4];
            #pragma unroll
            for (int m = 0; m < 4; ++m) al[m] = lds_frag128(sml, (spb + m * 16) * 128 + kb);
            #pragma unroll
            for (int m = 0; m < 4; ++m)
                #pragma unroll
                for (int n = 0; n < 2; ++n) acc[m][n] = MFMA(al[m], bh[n], acc[m][n]);
            // 2-term split
        }
    }
    float s4[2], b4[2];
    #pragma unroll
    for (int n = 0; n < 2; ++n) {
        s4[n] = sc[wc * 32 + n * 16 + l15];
        b4[n] = bi[wc * 32 + n * 16 + l15];
    }
    float* rowout = qb + ((size_t)(b * 128 + h) * 128) * 128;
    #pragma unroll
    for (int m = 0; m < 4; ++m)
        #pragma unroll
        for (int n = 0; n < 2; ++n)
            #pragma unroll
            for (int r = 0; r < 4; ++r) {
                int px = wr * 64 + m * 16 + l4 * 4 + r;
                int oc = wc * 32 + n * 16 + l15;
                rowout[px * 128 + oc] = acc[m][n][r] * s4[n] + b4[n];
            }
}

// ---------------- axial attention (row AND col in one launch) -> relu'd outputs ----------------
__global__ __launch_bounds__(128) void attn_kernel(const float* __restrict__ rowmean,
                                                   const float* __restrict__ colmean,
                                                   const float* __restrict__ pos_rq, const float* __restrict__ pos_rk,
                                                   const float* __restrict__ pos_cq, const float* __restrict__ pos_ck,
                                                   float* __restrict__ xr_act, float* __restrict__ xc_act) {
    __shared__ float qr[8][128], kr[8][128], vr[16][128];
    int iscol = blockIdx.x >> 6;
    int sub = blockIdx.x & 63;
    int b = sub >> 3, head = sub & 7;
    const float* meanbuf = iscol ? colmean : rowmean;
    const float* posq = iscol ? pos_cq : pos_rq;
    const float* posk = iscol ? pos_ck : pos_rk;
    float* xact = iscol ? xc_act : xr_act;
    int i = threadIdx.x;
    float src = (i + 0.5f) * 0.125f - 0.5f;
    src = fmaxf(src, 0.f);
    int i0 = (int)src;
    if (i0 > 15) i0 = 15;
    float f = src - (float)i0;
    int i1 = (i0 + 1 > 15) ? 15 : i0 + 1;
    const float* mb = meanbuf + (size_t)b * 256 * 128;
    for (int kd = 0; kd < 8; ++kd) {
        int cq = head * 8 + kd;
        qr[kd][i] = mb[cq * 128 + i] + posq[cq * 16 + i0] * (1.f - f) + posq[cq * 16 + i1] * f;
        kr[kd][i] = mb[(64 + cq) * 128 + i] + posk[cq * 16 + i0] * (1.f - f) + posk[cq * 16 + i1] * f;
    }
    for (int d = 0; d < 16; ++d)
        vr[d][i] = mb[(128 + head * 16 + d) * 128 + i];
    __syncthreads();
    float qreg[8];
    #pragma unroll
    for (int kd = 0; kd < 8; ++kd) qreg[kd] = qr[kd][i];
    const float scale = 0.35355339059327373f;
    float m = -INFINITY;
    for (int j = 0; j < 128; ++j) {
        float sj = 0.f;
        #pragma unroll
        for (int kd = 0; kd < 8; ++kd) sj += qreg[kd] * kr[kd][j];
        m = fmaxf(m, sj * scale);
    }
    float denom = 0.f;
    float acc[16];
    #pragma unroll
    for (int d = 0; d < 16; ++d) acc[d] = 0.f;
    for (int j = 0; j < 128; ++j) {
        float sj = 0.f;
        #pragma unroll
        for (int kd = 0; kd < 8; ++kd) sj += qreg[kd] * kr[kd][j];
        float pj = __expf(sj * scale - m);
        denom += pj;
        #pragma unroll
        for (int d = 0; d < 16; ++d) acc[d] += pj * vr[d][j];
    }
    float inv = __builtin_amdgcn_rcpf(denom);
    float* xp = xact + ((size_t)b * 128 + head * 16) * 128;
    for (int d = 0; d < 16; ++d)
        xp[d * 128 + i] = fmaxf(acc[d] * inv, 0.f);
}

// ---------------- 1x1 conv on xr/xc + BN -> TRANSPOSED [b][i][ic] outputs ----------------
__global__ __launch_bounds__(256) void rc_conv_kernel(const float* __restrict__ xr_act, const float* __restrict__ xc_act,
                                                      const float* __restrict__ wrowT, const float* __restrict__ wcolT,
                                                      const float* __restrict__ rs, const float* __restrict__ rb,
                                                      const float* __restrict__ cs, const float* __restrict__ cb,
                                                      float* __restrict__ xrT, float* __restrict__ xcT) {
    __shared__ float4 lds[128][16];
    int blk = blockIdx.x;             // 0..31
    int iscol = blk >> 4;
    int rem = blk & 15;
    int b = rem >> 1;
    int i0 = (rem & 1) * 64;
    const float* src = iscol ? xc_act : xr_act;
    const float* wT  = iscol ? wcolT : wrowT;
    const float* ss  = iscol ? cs : rs;
    const float* sb  = iscol ? cb : rb;
    float* dst       = iscol ? xcT : xrT;
    int tid = threadIdx.x;
    const float4* src4 = (const float4*)(src + (size_t)b * 16384 + i0);
    for (int idx = tid; idx < 128 * 16; idx += 256) {
        int ic = idx >> 4, q = idx & 15;
        lds[ic][q] = src4[ic * 32 + q];
    }
    __syncthreads();
    int oc = tid & 127, sub = tid >> 7;
    float4 acc[8];
    #pragma unroll
    for (int q = 0; q < 8; ++q) acc[q] = make_float4(0.f, 0.f, 0.f, 0.f);
    for (int ic = 0; ic < 128; ++ic) {
        float w = wT[ic * 128 + oc];
        #pragma unroll
        for (int q = 0; q < 8; ++q) {
            float4 v = lds[ic][sub * 8 + q];
            acc[q].x += w * v.x; acc[q].y += w * v.y;
            acc[q].z += w * v.z; acc[q].w += w * v.w;
        }
    }
    float s = ss[oc], bb = sb[oc];
    int ibase = i0 + sub * 32;
    #pragma unroll
    for (int q = 0; q < 8; ++q) {
        float vv[4] = {acc[q].x, acc[q].y, acc[q].z, acc[q].w};
        #pragma unroll
        for (int r = 0; r < 4; ++r) {
            int i = ibase + q * 4 + r;
            dst[((size_t)b * 128 + i) * 128 + oc] = vv[r] * s + bb;
        }
    }
}

// ---------------- final: xx=v+xr+xc, relu, proj MFMA + BN, hsig*qkv_b -> out NCHW ----------------
__global__ __launch_bounds__(512) void final_mfma(const float* __restrict__ qf,
                                                  const float* __restrict__ xrT, const float* __restrict__ xcT,
                                                  const short* __restrict__ wproj_h,
                                                  const float* __restrict__ ps, const float* __restrict__ pb,
                                                  const float* __restrict__ qb, float* __restrict__ out) {
    __shared__ char sm[69632];
    short* ahi = (short*)sm;              // [128][136]
    short* alo = (short*)(sm + 34816);    // [128][136]
    int flat = blockIdx.x;
    int b = flat & 7, h = flat >> 3;
    int tid = threadIdx.x, lane = tid & 63, wid = tid >> 6;
    int wr = wid >> 2, wc = wid & 3;      // px half / oc quarter (32 oc)
    int l15 = lane & 15, l4 = lane >> 4;
    int spb = wr * 64 + l15;
    int ocb = wc * 32 + l15;
    for (int i = 0; i < 4; ++i) {
        int idx = tid + i * 512;          // 2048 = 128px x 16 groups
        int px = idx >> 4, g = idx & 15;
        const float* vp = qf + ((size_t)((b * 128 + h) * 128 + px)) * 256 + 128 + g * 8;
        float4 v0 = *(const float4*)vp;
        float4 v1 = *(const float4*)(vp + 4);
        float vv[8] = {v0.x, v0.y, v0.z, v0.w, v1.x, v1.y, v1.z, v1.w};
        const float* xr = xrT + ((size_t)(b * 128 + h)) * 128 + g * 8;
        const float* xc = xcT + ((size_t)(b * 128 + px)) * 128 + g * 8;
        short8 hv, lv;
        #pragma unroll
        for (int k = 0; k < 8; ++k) {
            float v = vv[k] + xr[k] + xc[k];
            v = fmaxf(v, 0.f);
            unsigned u = packhl(v);
            hv[k] = (short)(u & 0xFFFFu);
            lv[k] = (short)(u >> 16);
        }
        *(short8*)(ahi + px * 136 + g * 8) = hv;
        *(short8*)(alo + px * 136 + g * 8) = lv;
    }
    __syncthreads();
    f32x4 acc[4][2];
    #pragma unroll
    for (int m = 0; m < 4; ++m)
        #pragma unroll
        for (int n = 0; n < 2; ++n) acc[m][n] = (f32x4){0.f, 0.f, 0.f, 0.f};
    #pragma unroll
    for (int ks = 0; ks < 4; ++ks) {
        int ko = ks * 32 + l4 * 8;
        short8 ah[4], bh[2];
        #pragma unroll
        for (int m = 0; m < 4; ++m) ah[m] = *(const short8*)(ahi + (spb + m * 16) * 136 + ko);
        #pragma unroll
        for (int n = 0; n < 2; ++n) bh[n] = *(const short8*)(wproj_h + (ocb + n * 16) * 128 + ko);
        #pragma unroll
        for (int m = 0; m < 4; ++m)
            #pragma unroll
            for (int n = 0; n < 2; ++n) acc[m][n] = MFMA(ah[m], bh[n], acc[m][n]);
        short8 al[4];
        #pragma unroll
        for (int m = 0; m < 4; ++m) al[m] = *(const short8*)(alo + (spb + m * 16) * 136 + ko);
        #pragma unroll
        for (int m = 0; m < 4; ++m)
            #pragma unroll
            for (int n = 0; n < 2; ++n) acc[m][n] = MFMA(al[m], bh[n], acc[m][n]);
        // 2-term split
    }
    float s4[2], b4[2];
    #pragma unroll
    for (int n = 0; n < 2; ++n) {
        s4[n] = ps[wc * 32 + n * 16 + l15];
        b4[n] = pb[wc * 32 + n * 16 + l15];
    }
    float* tr = (float*)sm;    // [64 ocl][129 px]
    #pragma unroll 1
    for (int p = 0; p < 2; ++p) {
        __syncthreads();
        if ((wc >> 1) == p) {
            #pragma unroll
            for (int n = 0; n < 2; ++n)
                #pragma unroll
                for (int m = 0; m < 4; ++m)
                    #pragma unroll
                    for (int r = 0; r < 4; ++r) {
                        int px = wr * 64 + m * 16 + l4 * 4 + r;
                        int ocl = (wc & 1) * 32 + n * 16 + l15;    // 0..63 within half
                        int oc = p * 64 + ocl;
                        float val = acc[m][n][r] * s4[n] + b4[n];
                        float hs = fminf(fmaxf(val + 3.f, 0.f), 6.f) * (1.f / 6.f);
                        float g = qb[((size_t)((b * 128 + h) * 128 + px)) * 128 + oc];
                        tr[ocl * 129 + px] = hs * g;
                    }
        }
        __syncthreads();
        int ocl = tid >> 3, q = tid & 7;      // 64 ocl x 8 q
        int oc = p * 64 + ocl;
        float* yp = out + (size_t)(b * 128 + oc) * S + h * 128 + q * 16;
        #pragma unroll
        for (int j = 0; j < 16; j += 4) {
            float4 v;
            v.x = tr[ocl * 129 + q * 16 + j];
            v.y = tr[ocl * 129 + q * 16 + j + 1];
            v.z = tr[ocl * 129 + q * 16 + j + 2];
            v.w = tr[ocl * 129 + q * 16 + j + 3];
            *(float4*)(yp + j) = v;
        }
    }
}

extern "C" void kernel_launch(void* const* d_in, const int* in_sizes, int n_in,
                              void* d_out, int out_size, void* d_ws, size_t ws_size,
                              hipStream_t stream) {
    const float* x       = (const float*)d_in[0];
    const float* bn1_s   = (const float*)d_in[1];
    const float* bn1_b   = (const float*)d_in[2];
    const float* fc1_w   = (const float*)d_in[3];
    const float* fc1_b   = (const float*)d_in[4];
    const float* wq      = (const float*)d_in[5];
    const float* bnq_s   = (const float*)d_in[6];
    const float* bnq_b   = (const float*)d_in[7];
    const float* wk      = (const float*)d_in[8];
    const float* bnk_s   = (const float*)d_in[9];
    const float* bnk_b   = (const float*)d_in[10];
    const float* wv      = (const float*)d_in[11];
    const float* bnv_s   = (const float*)d_in[12];
    const float* bnv_b   = (const float*)d_in[13];
    const float* pos_rq  = (const float*)d_in[14];
    const float* pos_rk  = (const float*)d_in[15];
    const float* pos_cq  = (const float*)d_in[16];
    const float* pos_ck  = (const float*)d_in[17];
    const float* wrow    = (const float*)d_in[18];
    const float* bnrow_s = (const float*)d_in[19];
    const float* bnrow_b = (const float*)d_in[20];
    const float* wcol    = (const float*)d_in[21];
    const float* bncol_s = (const float*)d_in[22];
    const float* bncol_b = (const float*)d_in[23];
    const float* wproj   = (const float*)d_in[24];
    const float* bnproj_s= (const float*)d_in[25];
    const float* bnproj_b= (const float*)d_in[26];
    const float* wdw     = (const float*)d_in[27];
    const float* bndw_s  = (const float*)d_in[28];
    const float* bndw_b  = (const float*)d_in[29];
    const float* wpw     = (const float*)d_in[30];
    const float* bnpw_s  = (const float*)d_in[31];
    const float* bnpw_b  = (const float*)d_in[32];

    char* ws = (char*)d_ws;
    short* t0ph  = (short*)(ws);                        // 34,611,200  [8][130][130][128]
    short* t0pl  = (short*)(ws + (size_t)34611200);     // 34,611,200
    float* qkvf  = (float*)(ws + (size_t)136331264);    // 134,217,728 [8][128][128][256] f32
    float* qkvb  = (float*)(ws + (size_t)270548992);    // 67,108,864  [8][128][128][128] f32
    char* sp = ws + (size_t)337657856;
    float* rowmean = (float*)sp; sp += 1048576;
    float* colmean = (float*)sp; sp += 1048576;
    float* xr_act  = (float*)sp; sp += 524288;
    float* xc_act  = (float*)sp; sp += 524288;
    float* xrT     = (float*)sp; sp += 524288;
    float* xcT     = (float*)sp; sp += 524288;
    short* wch     = (short*)sp; sp += 294912;
    short* wcl     = (short*)sp; sp += 294912;   // unused (2-term)
    short* wqkv_h  = (short*)sp; sp += 65536;
    short* wqkv_l  = (short*)sp; sp += 65536;    // unused
    short* wpw_h   = (short*)sp; sp += 65536;
    short* wpw_l   = (short*)sp; sp += 65536;    // unused
    short* wproj_h = (short*)sp; sp += 32768;
    short* wproj_l = (short*)sp; sp += 32768;    // unused
    float* wrowT   = (float*)sp; sp += 65536;
    float* wcolT   = (float*)sp; sp += 65536;
    float* sqkv    = (float*)sp; sp += 1024;
    float* bqkv    = (float*)sp; sp += 1024;
    float* wdwT    = (float*)sp; sp += 9216;
    (void)wcl; (void)wqkv_l; (void)wpw_l; (void)wproj_l;

    float* out = (float*)d_out;

    prep_kernel<<<576, 256, 0, stream>>>(wq, wk, wv, bnq_s, bnq_b, bnk_s, bnk_b, bnv_s, bnv_b,
                                         wpw, wproj, wrow, wcol, fc1_w, wdw,
                                         wqkv_h, sqkv, bqkv, wpw_h,
                                         wproj_h, wrowT, wcolT, wch, wdwT,
                                         t0ph, t0pl);
    pool_kernel<<<dim3(256, 8), 256, 0, stream>>>(x, bn1_s, bn1_b, t0ph, t0pl);
    convqkv_mfma<<<1024, 512, 0, stream>>>(t0ph, t0pl, wch, fc1_b,
                                           wqkv_h, sqkv, bqkv, qkvf, rowmean);
    colmean_kernel<<<1024, 256, 0, stream>>>(qkvf, colmean);
    dwpw_mfma<<<1024, 512, 0, stream>>>(qkvf, wdwT, bndw_s, bndw_b,
                                        wpw_h, bnpw_s, bnpw_b, qkvb);
    attn_kernel<<<128, 128, 0, stream>>>(rowmean, colmean, pos_rq, pos_rk, pos_cq, pos_ck,
                                         xr_act, xc_act);
    rc_conv_kernel<<<32, 256, 0, stream>>>(xr_act, xc_act, wrowT, wcolT,
                                           bnrow_s, bnrow_b, bncol_s, bncol_b, xrT, xcT);
    final_mfma<<<1024, 512, 0, stream>>>(qkvf, xrT, xcT, wproj_h,
                                         bnproj_s, bnproj_b, qkvb, out);
}

// Round 20
// 476.926 us; speedup vs baseline: 1.0242x; 1.0242x over previous
//
#include <hip/hip_runtime.h>
#include <math.h>

#define S 16384      // 128*128 spatial
#define HW 128

typedef __attribute__((ext_vector_type(8))) short short8;
typedef __attribute__((ext_vector_type(4))) float f32x4;

__device__ __forceinline__ float mishf(float t) {
    float sp = (t > 20.0f) ? t : __logf(1.0f + __expf(t));
    float e2 = __expf(-2.0f * sp);
    return t * (1.0f - e2) * __builtin_amdgcn_rcpf(1.0f + e2);
}
__device__ __forceinline__ short f2bf(float f) {   // RNE f32 -> bf16 bits
    unsigned u = __float_as_uint(f);
    unsigned r = (u + 0x7FFFu + ((u >> 16) & 1u)) >> 16;
    return (short)r;
}
__device__ __forceinline__ float bf2f(short s) {
    unsigned u = ((unsigned)(unsigned short)s) << 16;
    return __uint_as_float(u);
}
__device__ __forceinline__ unsigned packhl(float v) {  // lo16=hi part, hi16=lo part
    short h = f2bf(v);
    short l = f2bf(v - bf2f(h));
    return (unsigned)(unsigned short)h | ((unsigned)(unsigned short)l << 16);
}
__device__ __forceinline__ void gl_lds16(const void* g, void* l) {
    __builtin_amdgcn_global_load_lds(
        (const __attribute__((address_space(1))) unsigned int*)g,
        (__attribute__((address_space(3))) unsigned int*)l, 16, 0, 0);
}
// swizzled LDS fragment read for [px][256B] rows
__device__ __forceinline__ short8 lds_frag(const char* base, int a) {
    int p = a ^ (((a >> 8) & 7) << 4);
    return *(const short8*)(base + p);
}
// swizzled LDS fragment read for [px][128B] rows
__device__ __forceinline__ short8 lds_frag128(const char* base, int a) {
    int p = a ^ (((a >> 7) & 7) << 4);
    return *(const short8*)(base + p);
}
__device__ __forceinline__ int swz128(int a) { return a ^ (((a >> 7) & 7) << 4); }
#define MFMA(a, b, c) __builtin_amdgcn_mfma_f32_16x16x32_bf16(a, b, c, 0, 0, 0)

// ---------------- prep: bf16 weights (2-term scheme) + zero t0p borders ----------------
__global__ void prep_kernel(const float* __restrict__ wq, const float* __restrict__ wk, const float* __restrict__ wv,
                            const float* __restrict__ bnq_s, const float* __restrict__ bnq_b,
                            const float* __restrict__ bnk_s, const float* __restrict__ bnk_b,
                            const float* __restrict__ bnv_s, const float* __restrict__ bnv_b,
                            const float* __restrict__ wpw, const float* __restrict__ wproj,
                            const float* __restrict__ wrow, const float* __restrict__ wcol,
                            const float* __restrict__ fc1_w, const float* __restrict__ wdw,
                            short* __restrict__ wqkv_h,
                            float* __restrict__ sqkv, float* __restrict__ bqkv,
                            short* __restrict__ wpw_h,
                            short* __restrict__ wproj_h,
                            float* __restrict__ wrowT, float* __restrict__ wcolT,
                            short* __restrict__ wch,
                            float* __restrict__ wdwT,
                            short* __restrict__ t0ph, short* __restrict__ t0pl) {
    int tid = blockIdx.x * 256 + threadIdx.x;
    if (tid < 256 * 128) {            // wqkv [oc 256][ic 128] bf16
        int oc = tid >> 7, ic = tid & 127;
        float w = (oc < 64) ? wq[oc * 128 + ic]
                : (oc < 128) ? wk[(oc - 64) * 128 + ic]
                : wv[(oc - 128) * 128 + ic];
        wqkv_h[tid] = f2bf(w);
    }
    if (tid < 256) {
        sqkv[tid] = (tid < 64) ? bnq_s[tid] : (tid < 128) ? bnk_s[tid - 64] : bnv_s[tid - 128];
        bqkv[tid] = (tid < 64) ? bnq_b[tid] : (tid < 128) ? bnk_b[tid - 64] : bnv_b[tid - 128];
    }
    if (tid < 128 * 256) {            // wpw [oc 128][ic 256] bf16
        wpw_h[tid] = f2bf(wpw[tid]);
    }
    if (tid < 128 * 128) {
        wproj_h[tid] = f2bf(wproj[tid]);   // [oc][ic]
        int ic = tid >> 7, oc = tid & 127;
        wrowT[tid] = wrow[oc * 128 + ic];
        wcolT[tid] = wcol[oc * 128 + ic];
    }
    if (tid < 9 * 128 * 128) {        // conv3x3 [tap][oc][ic] bf16
        int tap = tid >> 14;
        int oc = (tid >> 7) & 127;
        int ic = tid & 127;
        wch[tid] = f2bf(fc1_w[(oc * 128 + ic) * 9 + tap]);
    }
    if (tid < 9 * 256) {              // depthwise [tap][c]
        int tap = tid / 256, c = tid % 256;
        wdwT[tap * 256 + c] = wdw[c * 9 + tap];
    }
    if (tid < 132096) {               // border zero
        int bb = tid / 16512;
        int rem = tid - bb * 16512;
        int part = rem / 8256;
        int e = rem - part * 8256;
        short* p = part ? t0pl : t0ph;
        size_t ib = (size_t)bb * 130 * 130 * 128;
        short8 z = (short8){0, 0, 0, 0, 0, 0, 0, 0};
        if (e < 4160) {
            int row = (e < 2080) ? 0 : 129;
            int off = (e % 2080) * 8;
            *(short8*)(p + ib + (size_t)row * 130 * 128 + off) = z;
        } else {
            int e2 = e - 4160;
            int row = 1 + (e2 >> 5);
            int side = (e2 >> 4) & 1;
            int off = (e2 & 15) * 8;
            *(short8*)(p + ib + ((size_t)row * 130 + (side ? 129 : 0)) * 128 + off) = z;
        }
    }
}

// ---------------- pool (avg+max) + BN + Mish -> padded NHWC split bf16 ----------------
__global__ __launch_bounds__(256) void pool_kernel(const float* __restrict__ x,
                                                   const float* __restrict__ s1, const float* __restrict__ b1,
                                                   short* __restrict__ t0ph, short* __restrict__ t0pl) {
    __shared__ unsigned ot[64][132];
    int bx = blockIdx.x;               // 0..255
    int b = blockIdx.y;
    int h = bx >> 1, wh = bx & 1;
    int t = threadIdx.x;
    int wp = t & 31;                   // w-pair index (2 outputs each)
    int c8 = t >> 5;                   // 0..7
    int w0 = wh * 64 + wp * 2;
    for (int cs = 0; cs < 8; ++cs) {
        int c = cs * 8 + c8;           // 0..63
        const float* xp = x + (size_t)(b * 64 + c) * 65536;
        float vs[3][5], vm[3][5];
        #pragma unroll
        for (int kh = 0; kh < 3; ++kh) {
            int ih = 2 * h + kh - 1;
            bool hok = (unsigned)ih < 256u;
            #pragma unroll
            for (int j = 0; j < 5; ++j) {
                int iw = 2 * w0 - 1 + j;
                bool ok = hok && (unsigned)iw < 256u;
                float v = ok ? xp[ih * 256 + iw] : 0.f;
                vs[kh][j] = ok ? v : 0.f;
                vm[kh][j] = ok ? v : -INFINITY;
            }
        }
        #pragma unroll
        for (int o = 0; o < 2; ++o) {
            float sum = 0.f, mx = -INFINITY;
            #pragma unroll
            for (int kh = 0; kh < 3; ++kh)
                #pragma unroll
                for (int kw = 0; kw < 3; ++kw) {
                    sum += vs[kh][kw + 2 * o];
                    mx = fmaxf(mx, vm[kh][kw + 2 * o]);
                }
            float ta = mishf((sum * (1.f / 9.f)) * s1[c] + b1[c]);
            float tm = mishf(mx * s1[64 + c] + b1[64 + c]);
            ot[wp * 2 + o][c] = packhl(ta);
            ot[wp * 2 + o][64 + c] = packhl(tm);
        }
    }
    __syncthreads();
    size_t rowbase = ((size_t)(b * 130 + h + 1) * 130 + 1 + wh * 64) * 128;
    short* oph = t0ph + rowbase;
    short* opl = t0pl + rowbase;
    for (int idx = t; idx < 64 * 16; idx += 256) {
        int wloc = idx >> 4, co = idx & 15;
        short8 hv, lv;
        #pragma unroll
        for (int j = 0; j < 8; ++j) {
            unsigned u = ot[wloc][co * 8 + j];
            hv[j] = (short)(u & 0xFFFFu);
            lv[j] = (short)(u >> 16);
        }
        *(short8*)(oph + wloc * 128 + co * 8) = hv;
        *(short8*)(opl + wloc * 128 + co * 8) = lv;
    }
}

// ---------------- FUSED conv3x3 + qkv 1x1, 512 threads / 8 waves, 2-term split ----------------
__global__ __launch_bounds__(512) void convqkv_mfma(const short* __restrict__ t0ph,
                                                    const short* __restrict__ t0pl,
                                                    const short* __restrict__ wch,
                                                    const float* __restrict__ fb,
                                                    const short* __restrict__ wqkv_h,
                                                    const float* __restrict__ sc, const float* __restrict__ bi,
                                                    float* __restrict__ qf, float* __restrict__ rowmean) {
    __shared__ char sm[69632];          // staging 2x33792; reused as A-pack 2x[128][132]; rsum [2][256] at 67584
    char* smh = sm;
    char* sml = sm + 33792;
    float* rsum = (float*)(sm + 67584);
    int flat = blockIdx.x;              // 1024
    int b = flat & 7;                   // XCD-affine
    int h = flat >> 3;
    int tid = threadIdx.x, lane = tid & 63, wid = tid >> 6;
    int l15 = lane & 15, l4 = lane >> 4;
    int wrc = wid >> 2;                 // conv px half
    int wcc = wid & 3;                  // conv oc quarter (32 oc)
    int spbc = wrc * 64 + l15;
    int ocbc = wcc * 32 + l15;
    f32x4 acc[4][2];
    #pragma unroll
    for (int m = 0; m < 4; ++m)
        #pragma unroll
        for (int n = 0; n < 2; ++n) acc[m][n] = (f32x4){0.f, 0.f, 0.f, 0.f};
    for (int kh = 0; kh < 3; ++kh) {
        __syncthreads();
        const char* gh = (const char*)(t0ph + ((size_t)(b * 130 + h + kh) * 130) * 128);
        const char* gl = (const char*)(t0pl + ((size_t)(b * 130 + h + kh) * 130) * 128);
        #pragma unroll
        for (int it = 0; it < 5; ++it) {
            int idx = it * 512 + tid;           // 2080 x 16B per plane
            if (idx < 2080) {
                int dl = idx * 16;
                int srcoff = dl ^ (((dl >> 8) & 7) << 4);
                gl_lds16(gh + srcoff, smh + dl);
                gl_lds16(gl + srcoff, sml + dl);
            }
        }
        __syncthreads();
        #pragma unroll
        for (int kw = 0; kw < 3; ++kw) {
            const short* wbh = wch + (size_t)(kh * 3 + kw) * 16384;
            #pragma unroll
            for (int ks = 0; ks < 4; ++ks) {
                int kb = ks * 64 + l4 * 16;
                int kws = ks * 32 + l4 * 8;
                short8 ah[4], bh[2];
                #pragma unroll
                for (int m = 0; m < 4; ++m)
                    ah[m] = lds_frag(smh, ((spbc + m * 16 + kw) << 8) + kb);
                #pragma unroll
                for (int n = 0; n < 2; ++n)
                    bh[n] = *(const short8*)(wbh + (ocbc + n * 16) * 128 + kws);
                #pragma unroll
                for (int m = 0; m < 4; ++m)
                    #pragma unroll
                    for (int n = 0; n < 2; ++n)
                        acc[m][n] = MFMA(ah[m], bh[n], acc[m][n]);
                short8 al[4];
                #pragma unroll
                for (int m = 0; m < 4; ++m)
                    al[m] = lds_frag(sml, ((spbc + m * 16 + kw) << 8) + kb);
                #pragma unroll
                for (int m = 0; m < 4; ++m)
                    #pragma unroll
                    for (int n = 0; n < 2; ++n)
                        acc[m][n] = MFMA(al[m], bh[n], acc[m][n]);
                // 2-term: a_h*w_l dropped (weights bf16)
            }
        }
    }
    // pack conv output (y row) + bias into split-bf16 A tile in LDS
    float fbv[2];
    #pragma unroll
    for (int n = 0; n < 2; ++n) fbv[n] = fb[wcc * 32 + n * 16 + l15];
    rsum[tid] = 0.f;                    // 512 entries
    __syncthreads();
    short* ahi = (short*)sm;            // [128][132]
    short* alo = (short*)(sm + 33792);  // [128][132]
    #pragma unroll
    for (int m = 0; m < 4; ++m)
        #pragma unroll
        for (int n = 0; n < 2; ++n)
            #pragma unroll
            for (int r = 0; r < 4; ++r) {
                int px = wrc * 64 + m * 16 + l4 * 4 + r;
                int ocl = wcc * 32 + n * 16 + l15;
                unsigned u = packhl(acc[m][n][r] + fbv[n]);
                ahi[px * 132 + ocl] = (short)(u & 0xFFFFu);
                alo[px * 132 + ocl] = (short)(u >> 16);
            }
    __syncthreads();
    // qkv GEMM: A[128px][128ic] (LDS) x B[256oc][128ic], 8 waves, 2-term
    int spbq = wrc * 64 + l15;          // px half (reuse wrc)
    int ocbq = wcc * 64 + l15;          // oc quarter of 256 (64 oc)
    f32x4 aq[4][4];
    #pragma unroll
    for (int m = 0; m < 4; ++m)
        #pragma unroll
        for (int n = 0; n < 4; ++n) aq[m][n] = (f32x4){0.f, 0.f, 0.f, 0.f};
    #pragma unroll
    for (int ks = 0; ks < 4; ++ks) {
        int k0 = ks * 32 + l4 * 8;
        short8 ah[4], bh[4];
        #pragma unroll
        for (int m = 0; m < 4; ++m) ah[m] = *(const short8*)(ahi + (spbq + m * 16) * 132 + k0);
        #pragma unroll
        for (int n = 0; n < 4; ++n) bh[n] = *(const short8*)(wqkv_h + (size_t)(ocbq + n * 16) * 128 + k0);
        #pragma unroll
        for (int m = 0; m < 4; ++m)
            #pragma unroll
            for (int n = 0; n < 4; ++n) aq[m][n] = MFMA(ah[m], bh[n], aq[m][n]);
        short8 al[4];
        #pragma unroll
        for (int m = 0; m < 4; ++m) al[m] = *(const short8*)(alo + (spbq + m * 16) * 132 + k0);
        #pragma unroll
        for (int m = 0; m < 4; ++m)
            #pragma unroll
            for (int n = 0; n < 4; ++n) aq[m][n] = MFMA(al[m], bh[n], aq[m][n]);
        // 2-term: a_h*w_l dropped
    }
    // rowsum partials (raw acc; scale/bias at final store)
    #pragma unroll
    for (int n = 0; n < 4; ++n) {
        float v = 0.f;
        #pragma unroll
        for (int m = 0; m < 4; ++m)
            #pragma unroll
            for (int r = 0; r < 4; ++r) v += aq[m][n][r];
        v += __shfl_xor(v, 16);
        v += __shfl_xor(v, 32);
        if (l4 == 0) rsum[wrc * 256 + wcc * 64 + n * 16 + l15] = v;
    }
    // BN + direct f32 store
    float s4[4], b4[4];
    #pragma unroll
    for (int n = 0; n < 4; ++n) {
        s4[n] = sc[wcc * 64 + n * 16 + l15];
        b4[n] = bi[wcc * 64 + n * 16 + l15];
    }
    float* rowout = qf + ((size_t)(b * 128 + h) * 128) * 256;
    #pragma unroll
    for (int m = 0; m < 4; ++m)
        #pragma unroll
        for (int n = 0; n < 4; ++n)
            #pragma unroll
            for (int r = 0; r < 4; ++r) {
                int px = wrc * 64 + m * 16 + l4 * 4 + r;
                int oc = wcc * 64 + n * 16 + l15;
                rowout[px * 256 + oc] = aq[m][n][r] * s4[n] + b4[n];
            }
    __syncthreads();
    if (tid < 256)
        rowmean[((size_t)b * 256 + tid) * 128 + h] =
            (rsum[tid] + rsum[256 + tid]) * sc[tid] * (1.f / 128.f) + bi[tid];
}

// ---------------- colmean: mean over h of qkv f32 NHWC ----------------
__global__ __launch_bounds__(256) void colmean_kernel(const float* __restrict__ qf,
                                                      float* __restrict__ colmean) {
    __shared__ float red[8][256];
    int blk = blockIdx.x;                 // 1024
    int b = blk & 7, w = blk >> 3;        // XCD-affine
    int tid = threadIdx.x;
    int c8g = tid & 31;                   // channel group of 8
    int hs = tid >> 5;                    // 8 h-slices of 16
    float a8[8];
    #pragma unroll
    for (int k = 0; k < 8; ++k) a8[k] = 0.f;
    for (int j = 0; j < 16; ++j) {
        int h = hs * 16 + j;
        const float* p = qf + ((size_t)((b * 128 + h) * 128 + w)) * 256 + c8g * 8;
        float4 v0 = *(const float4*)p;
        float4 v1 = *(const float4*)(p + 4);
        a8[0] += v0.x; a8[1] += v0.y; a8[2] += v0.z; a8[3] += v0.w;
        a8[4] += v1.x; a8[5] += v1.y; a8[6] += v1.z; a8[7] += v1.w;
    }
    #pragma unroll
    for (int k = 0; k < 8; ++k) red[hs][c8g * 8 + k] = a8[k];
    __syncthreads();
    int c = tid;
    float s = 0.f;
    #pragma unroll
    for (int q = 0; q < 8; ++q) s += red[q][c];
    colmean[((size_t)b * 256 + c) * 128 + w] = s * (1.f / 128.f);
}

// ---------------- fused depthwise 3x3 + BN + ReLU + pointwise 256->128 MFMA + BN ----------------
// r18 form: 2 independent w outputs per thread, simple load flow (measured best).
__global__ __launch_bounds__(512) void dwpw_mfma(const float* __restrict__ qf,
                                                 const float* __restrict__ wdwT,
                                                 const float* __restrict__ ds, const float* __restrict__ db,
                                                 const short* __restrict__ wpw_h,
                                                 const float* __restrict__ sc, const float* __restrict__ bi,
                                                 float* __restrict__ qb) {
    __shared__ char sm[32768];
    char* smh = sm;           // dw out hi, [128w][128B] swizzled (64 c chunk)
    char* sml = sm + 16384;   // dw out lo
    int flat = blockIdx.x;
    int b = flat & 7, h = flat >> 3;
    int tid = threadIdx.x, lane = tid & 63, wid = tid >> 6;
    int wr = wid >> 2, wc = wid & 3;     // px half / oc quarter (32 oc)
    int l15 = lane & 15, l4 = lane >> 4;
    int spb = wr * 64 + l15;
    int ocb = wc * 32 + l15;
    int wdw_ = tid >> 3;      // 0..63 (w base, 2 w per thread)
    int c8t = tid & 7;        // c8 group within 64-c chunk
    f32x4 acc[4][2];
    #pragma unroll
    for (int m = 0; m < 4; ++m)
        #pragma unroll
        for (int n = 0; n < 2; ++n) acc[m][n] = (f32x4){0.f, 0.f, 0.f, 0.f};

    #pragma unroll 1
    for (int kc = 0; kc < 4; ++kc) {
        __syncthreads();      // previous chunk's MFMA reads done
        int cbase = kc * 64 + c8t * 8;
        #pragma unroll 1
        for (int i = 0; i < 2; ++i) {
            int w = wdw_ * 2 + i;
            float acc8[8];
            #pragma unroll
            for (int k = 0; k < 8; ++k) acc8[k] = 0.f;
            #pragma unroll
            for (int kh = 0; kh < 3; ++kh) {
                int ih = h + kh - 1;
                if ((unsigned)ih >= 128u) continue;
                #pragma unroll
                for (int kw = 0; kw < 3; ++kw) {
                    int iw = w + kw - 1;
                    if ((unsigned)iw >= 128u) continue;
                    const float* ip = qf + ((size_t)((b * 128 + ih) * 128 + iw)) * 256 + cbase;
                    float4 v0 = *(const float4*)ip;
                    float4 v1 = *(const float4*)(ip + 4);
                    const float* wp = wdwT + (kh * 3 + kw) * 256 + cbase;
                    acc8[0] += wp[0] * v0.x; acc8[1] += wp[1] * v0.y;
                    acc8[2] += wp[2] * v0.z; acc8[3] += wp[3] * v0.w;
                    acc8[4] += wp[4] * v1.x; acc8[5] += wp[5] * v1.y;
                    acc8[6] += wp[6] * v1.z; acc8[7] += wp[7] * v1.w;
                }
            }
            short8 hv, lv;
            #pragma unroll
            for (int k = 0; k < 8; ++k) {
                float v = fmaxf(acc8[k] * ds[cbase + k] + db[cbase + k], 0.f);
                unsigned u = packhl(v);
                hv[k] = (short)(u & 0xFFFFu);
                lv[k] = (short)(u >> 16);
            }
            int a = swz128(w * 128 + c8t * 16);
            *(short8*)(smh + a) = hv;
            *(short8*)(sml + a) = lv;
        }
        __syncthreads();
        #pragma unroll
        for (int ks = 0; ks < 2; ++ks) {
            int kb = ks * 64 + l4 * 16;               // byte offset in 128B row
            int kws = kc * 64 + ks * 32 + l4 * 8;     // weight short offset (ic)
            short8 ah[4], bh[2];
            #pragma unroll
            for (int m = 0; m < 4; ++m) ah[m] = lds_frag128(smh, (spb + m * 16) * 128 + kb);
            #pragma unroll
            for (int n = 0; n < 2; ++n) bh[n] = *(const short8*)(wpw_h + (ocb + n * 16) * 256 + kws);
            #pragma unroll
            for (int m = 0; m < 4; ++m)
                #pragma unroll
                for (int n = 0; n < 2; ++n) acc[m][n] = MFMA(ah[m], bh[n], acc[m][n]);
            short8 al[4];
            #pragma unroll
            for (int m = 0; m < 4; ++m) al[m] = lds_frag128(sml, (spb + m * 16) * 128 + kb);
            #pragma unroll
            for (int m = 0; m < 4; ++m)
                #pragma unroll
                for (int n = 0; n < 2; ++n) acc[m][n] = MFMA(al[m], bh[n], acc[m][n]);
            // 2-term split
        }
    }
    float s4[2], b4[2];
    #pragma unroll
    for (int n = 0; n < 2; ++n) {
        s4[n] = sc[wc * 32 + n * 16 + l15];
        b4[n] = bi[wc * 32 + n * 16 + l15];
    }
    float* rowout = qb + ((size_t)(b * 128 + h) * 128) * 128;
    #pragma unroll
    for (int m = 0; m < 4; ++m)
        #pragma unroll
        for (int n = 0; n < 2; ++n)
            #pragma unroll
            for (int r = 0; r < 4; ++r) {
                int px = wr * 64 + m * 16 + l4 * 4 + r;
                int oc = wc * 32 + n * 16 + l15;
                rowout[px * 128 + oc] = acc[m][n][r] * s4[n] + b4[n];
            }
}

// ---------------- axial attention (row AND col in one launch) -> relu'd outputs ----------------
__global__ __launch_bounds__(128) void attn_kernel(const float* __restrict__ rowmean,
                                                   const float* __restrict__ colmean,
                                                   const float* __restrict__ pos_rq, const float* __restrict__ pos_rk,
                                                   const float* __restrict__ pos_cq, const float* __restrict__ pos_ck,
                                                   float* __restrict__ xr_act, float* __restrict__ xc_act) {
    __shared__ float qr[8][128], kr[8][128], vr[16][128];
    int iscol = blockIdx.x >> 6;
    int sub = blockIdx.x & 63;
    int b = sub >> 3, head = sub & 7;
    const float* meanbuf = iscol ? colmean : rowmean;
    const float* posq = iscol ? pos_cq : pos_rq;
    const float* posk = iscol ? pos_ck : pos_rk;
    float* xact = iscol ? xc_act : xr_act;
    int i = threadIdx.x;
    float src = (i + 0.5f) * 0.125f - 0.5f;
    src = fmaxf(src, 0.f);
    int i0 = (int)src;
    if (i0 > 15) i0 = 15;
    float f = src - (float)i0;
    int i1 = (i0 + 1 > 15) ? 15 : i0 + 1;
    const float* mb = meanbuf + (size_t)b * 256 * 128;
    for (int kd = 0; kd < 8; ++kd) {
        int cq = head * 8 + kd;
        qr[kd][i] = mb[cq * 128 + i] + posq[cq * 16 + i0] * (1.f - f) + posq[cq * 16 + i1] * f;
        kr[kd][i] = mb[(64 + cq) * 128 + i] + posk[cq * 16 + i0] * (1.f - f) + posk[cq * 16 + i1] * f;
    }
    for (int d = 0; d < 16; ++d)
        vr[d][i] = mb[(128 + head * 16 + d) * 128 + i];
    __syncthreads();
    float qreg[8];
    #pragma unroll
    for (int kd = 0; kd < 8; ++kd) qreg[kd] = qr[kd][i];
    const float scale = 0.35355339059327373f;
    float m = -INFINITY;
    for (int j = 0; j < 128; ++j) {
        float sj = 0.f;
        #pragma unroll
        for (int kd = 0; kd < 8; ++kd) sj += qreg[kd] * kr[kd][j];
        m = fmaxf(m, sj * scale);
    }
    float denom = 0.f;
    float acc[16];
    #pragma unroll
    for (int d = 0; d < 16; ++d) acc[d] = 0.f;
    for (int j = 0; j < 128; ++j) {
        float sj = 0.f;
        #pragma unroll
        for (int kd = 0; kd < 8; ++kd) sj += qreg[kd] * kr[kd][j];
        float pj = __expf(sj * scale - m);
        denom += pj;
        #pragma unroll
        for (int d = 0; d < 16; ++d) acc[d] += pj * vr[d][j];
    }
    float inv = __builtin_amdgcn_rcpf(denom);
    float* xp = xact + ((size_t)b * 128 + head * 16) * 128;
    for (int d = 0; d < 16; ++d)
        xp[d * 128 + i] = fmaxf(acc[d] * inv, 0.f);
}

// ---------------- 1x1 conv on xr/xc + BN -> TRANSPOSED [b][i][ic] outputs ----------------
__global__ __launch_bounds__(256) void rc_conv_kernel(const float* __restrict__ xr_act, const float* __restrict__ xc_act,
                                                      const float* __restrict__ wrowT, const float* __restrict__ wcolT,
                                                      const float* __restrict__ rs, const float* __restrict__ rb,
                                                      const float* __restrict__ cs, const float* __restrict__ cb,
                                                      float* __restrict__ xrT, float* __restrict__ xcT) {
    __shared__ float4 lds[128][16];
    int blk = blockIdx.x;             // 0..31
    int iscol = blk >> 4;
    int rem = blk & 15;
    int b = rem >> 1;
    int i0 = (rem & 1) * 64;
    const float* src = iscol ? xc_act : xr_act;
    const float* wT  = iscol ? wcolT : wrowT;
    const float* ss  = iscol ? cs : rs;
    const float* sb  = iscol ? cb : rb;
    float* dst       = iscol ? xcT : xrT;
    int tid = threadIdx.x;
    const float4* src4 = (const float4*)(src + (size_t)b * 16384 + i0);
    for (int idx = tid; idx < 128 * 16; idx += 256) {
        int ic = idx >> 4, q = idx & 15;
        lds[ic][q] = src4[ic * 32 + q];
    }
    __syncthreads();
    int oc = tid & 127, sub = tid >> 7;
    float4 acc[8];
    #pragma unroll
    for (int q = 0; q < 8; ++q) acc[q] = make_float4(0.f, 0.f, 0.f, 0.f);
    for (int ic = 0; ic < 128; ++ic) {
        float w = wT[ic * 128 + oc];
        #pragma unroll
        for (int q = 0; q < 8; ++q) {
            float4 v = lds[ic][sub * 8 + q];
            acc[q].x += w * v.x; acc[q].y += w * v.y;
            acc[q].z += w * v.z; acc[q].w += w * v.w;
        }
    }
    float s = ss[oc], bb = sb[oc];
    int ibase = i0 + sub * 32;
    #pragma unroll
    for (int q = 0; q < 8; ++q) {
        float vv[4] = {acc[q].x, acc[q].y, acc[q].z, acc[q].w};
        #pragma unroll
        for (int r = 0; r < 4; ++r) {
            int i = ibase + q * 4 + r;
            dst[((size_t)b * 128 + i) * 128 + oc] = vv[r] * s + bb;
        }
    }
}

// ---------------- final: xx=v+xr+xc, relu, proj MFMA + BN, hsig*qkv_b -> out NCHW ----------------
__global__ __launch_bounds__(512) void final_mfma(const float* __restrict__ qf,
                                                  const float* __restrict__ xrT, const float* __restrict__ xcT,
                                                  const short* __restrict__ wproj_h,
                                                  const float* __restrict__ ps, const float* __restrict__ pb,
                                                  const float* __restrict__ qb, float* __restrict__ out) {
    __shared__ char sm[69632];
    short* ahi = (short*)sm;              // [128][136]
    short* alo = (short*)(sm + 34816);    // [128][136]
    int flat = blockIdx.x;
    int b = flat & 7, h = flat >> 3;
    int tid = threadIdx.x, lane = tid & 63, wid = tid >> 6;
    int wr = wid >> 2, wc = wid & 3;      // px half / oc quarter (32 oc)
    int l15 = lane & 15, l4 = lane >> 4;
    int spb = wr * 64 + l15;
    int ocb = wc * 32 + l15;
    for (int i = 0; i < 4; ++i) {
        int idx = tid + i * 512;          // 2048 = 128px x 16 groups
        int px = idx >> 4, g = idx & 15;
        const float* vp = qf + ((size_t)((b * 128 + h) * 128 + px)) * 256 + 128 + g * 8;
        float4 v0 = *(const float4*)vp;
        float4 v1 = *(const float4*)(vp + 4);
        float vv[8] = {v0.x, v0.y, v0.z, v0.w, v1.x, v1.y, v1.z, v1.w};
        const float* xr = xrT + ((size_t)(b * 128 + h)) * 128 + g * 8;
        const float* xc = xcT + ((size_t)(b * 128 + px)) * 128 + g * 8;
        short8 hv, lv;
        #pragma unroll
        for (int k = 0; k < 8; ++k) {
            float v = vv[k] + xr[k] + xc[k];
            v = fmaxf(v, 0.f);
            unsigned u = packhl(v);
            hv[k] = (short)(u & 0xFFFFu);
            lv[k] = (short)(u >> 16);
        }
        *(short8*)(ahi + px * 136 + g * 8) = hv;
        *(short8*)(alo + px * 136 + g * 8) = lv;
    }
    __syncthreads();
    f32x4 acc[4][2];
    #pragma unroll
    for (int m = 0; m < 4; ++m)
        #pragma unroll
        for (int n = 0; n < 2; ++n) acc[m][n] = (f32x4){0.f, 0.f, 0.f, 0.f};
    #pragma unroll
    for (int ks = 0; ks < 4; ++ks) {
        int ko = ks * 32 + l4 * 8;
        short8 ah[4], bh[2];
        #pragma unroll
        for (int m = 0; m < 4; ++m) ah[m] = *(const short8*)(ahi + (spb + m * 16) * 136 + ko);
        #pragma unroll
        for (int n = 0; n < 2; ++n) bh[n] = *(const short8*)(wproj_h + (ocb + n * 16) * 128 + ko);
        #pragma unroll
        for (int m = 0; m < 4; ++m)
            #pragma unroll
            for (int n = 0; n < 2; ++n) acc[m][n] = MFMA(ah[m], bh[n], acc[m][n]);
        short8 al[4];
        #pragma unroll
        for (int m = 0; m < 4; ++m) al[m] = *(const short8*)(alo + (spb + m * 16) * 136 + ko);
        #pragma unroll
        for (int m = 0; m < 4; ++m)
            #pragma unroll
            for (int n = 0; n < 2; ++n) acc[m][n] = MFMA(al[m], bh[n], acc[m][n]);
        // 2-term split
    }
    float s4[2], b4[2];
    #pragma unroll
    for (int n = 0; n < 2; ++n) {
        s4[n] = ps[wc * 32 + n * 16 + l15];
        b4[n] = pb[wc * 32 + n * 16 + l15];
    }
    float* tr = (float*)sm;    // [64 ocl][129 px]
    #pragma unroll 1
    for (int p = 0; p < 2; ++p) {
        __syncthreads();
        if ((wc >> 1) == p) {
            #pragma unroll
            for (int n = 0; n < 2; ++n)
                #pragma unroll
                for (int m = 0; m < 4; ++m)
                    #pragma unroll
                    for (int r = 0; r < 4; ++r) {
                        int px = wr * 64 + m * 16 + l4 * 4 + r;
                        int ocl = (wc & 1) * 32 + n * 16 + l15;    // 0..63 within half
                        int oc = p * 64 + ocl;
                        float val = acc[m][n][r] * s4[n] + b4[n];
                        float hs = fminf(fmaxf(val + 3.f, 0.f), 6.f) * (1.f / 6.f);
                        float g = qb[((size_t)((b * 128 + h) * 128 + px)) * 128 + oc];
                        tr[ocl * 129 + px] = hs * g;
                    }
        }
        __syncthreads();
        int ocl = tid >> 3, q = tid & 7;      // 64 ocl x 8 q
        int oc = p * 64 + ocl;
        float* yp = out + (size_t)(b * 128 + oc) * S + h * 128 + q * 16;
        #pragma unroll
        for (int j = 0; j < 16; j += 4) {
            float4 v;
            v.x = tr[ocl * 129 + q * 16 + j];
            v.y = tr[ocl * 129 + q * 16 + j + 1];
            v.z = tr[ocl * 129 + q * 16 + j + 2];
            v.w = tr[ocl * 129 + q * 16 + j + 3];
            *(float4*)(yp + j) = v;
        }
    }
}

extern "C" void kernel_launch(void* const* d_in, const int* in_sizes, int n_in,
                              void* d_out, int out_size, void* d_ws, size_t ws_size,
                              hipStream_t stream) {
    const float* x       = (const float*)d_in[0];
    const float* bn1_s   = (const float*)d_in[1];
    const float* bn1_b   = (const float*)d_in[2];
    const float* fc1_w   = (const float*)d_in[3];
    const float* fc1_b   = (const float*)d_in[4];
    const float* wq      = (const float*)d_in[5];
    const float* bnq_s   = (const float*)d_in[6];
    const float* bnq_b   = (const float*)d_in[7];
    const float* wk      = (const float*)d_in[8];
    const float* bnk_s   = (const float*)d_in[9];
    const float* bnk_b   = (const float*)d_in[10];
    const float* wv      = (const float*)d_in[11];
    const float* bnv_s   = (const float*)d_in[12];
    const float* bnv_b   = (const float*)d_in[13];
    const float* pos_rq  = (const float*)d_in[14];
    const float* pos_rk  = (const float*)d_in[15];
    const float* pos_cq  = (const float*)d_in[16];
    const float* pos_ck  = (const float*)d_in[17];
    const float* wrow    = (const float*)d_in[18];
    const float* bnrow_s = (const float*)d_in[19];
    const float* bnrow_b = (const float*)d_in[20];
    const float* wcol    = (const float*)d_in[21];
    const float* bncol_s = (const float*)d_in[22];
    const float* bncol_b = (const float*)d_in[23];
    const float* wproj   = (const float*)d_in[24];
    const float* bnproj_s= (const float*)d_in[25];
    const float* bnproj_b= (const float*)d_in[26];
    const float* wdw     = (const float*)d_in[27];
    const float* bndw_s  = (const float*)d_in[28];
    const float* bndw_b  = (const float*)d_in[29];
    const float* wpw     = (const float*)d_in[30];
    const float* bnpw_s  = (const float*)d_in[31];
    const float* bnpw_b  = (const float*)d_in[32];

    char* ws = (char*)d_ws;
    short* t0ph  = (short*)(ws);                        // 34,611,200  [8][130][130][128]
    short* t0pl  = (short*)(ws + (size_t)34611200);     // 34,611,200
    float* qkvf  = (float*)(ws + (size_t)136331264);    // 134,217,728 [8][128][128][256] f32
    float* qkvb  = (float*)(ws + (size_t)270548992);    // 67,108,864  [8][128][128][128] f32
    char* sp = ws + (size_t)337657856;
    float* rowmean = (float*)sp; sp += 1048576;
    float* colmean = (float*)sp; sp += 1048576;
    float* xr_act  = (float*)sp; sp += 524288;
    float* xc_act  = (float*)sp; sp += 524288;
    float* xrT     = (float*)sp; sp += 524288;
    float* xcT     = (float*)sp; sp += 524288;
    short* wch     = (short*)sp; sp += 294912;
    short* wqkv_h  = (short*)sp; sp += 65536;
    short* wpw_h   = (short*)sp; sp += 65536;
    short* wproj_h = (short*)sp; sp += 32768;
    float* wrowT   = (float*)sp; sp += 65536;
    float* wcolT   = (float*)sp; sp += 65536;
    float* sqkv    = (float*)sp; sp += 1024;
    float* bqkv    = (float*)sp; sp += 1024;
    float* wdwT    = (float*)sp; sp += 9216;

    float* out = (float*)d_out;

    prep_kernel<<<576, 256, 0, stream>>>(wq, wk, wv, bnq_s, bnq_b, bnk_s, bnk_b, bnv_s, bnv_b,
                                         wpw, wproj, wrow, wcol, fc1_w, wdw,
                                         wqkv_h, sqkv, bqkv, wpw_h,
                                         wproj_h, wrowT, wcolT, wch, wdwT,
                                         t0ph, t0pl);
    pool_kernel<<<dim3(256, 8), 256, 0, stream>>>(x, bn1_s, bn1_b, t0ph, t0pl);
    convqkv_mfma<<<1024, 512, 0, stream>>>(t0ph, t0pl, wch, fc1_b,
                                           wqkv_h, sqkv, bqkv, qkvf, rowmean);
    colmean_kernel<<<1024, 256, 0, stream>>>(qkvf, colmean);
    dwpw_mfma<<<1024, 512, 0, stream>>>(qkvf, wdwT, bndw_s, bndw_b,
                                        wpw_h, bnpw_s, bnpw_b, qkvb);
    attn_kernel<<<128, 128, 0, stream>>>(rowmean, colmean, pos_rq, pos_rk, pos_cq, pos_ck,
                                         xr_act, xc_act);
    rc_conv_kernel<<<32, 256, 0, stream>>>(xr_act, xc_act, wrowT, wcolT,
                                           bnrow_s, bnrow_b, bncol_s, bncol_b, xrT, xcT);
    final_mfma<<<1024, 512, 0, stream>>>(qkvf, xrT, xcT, wproj_h,
                                         bnproj_s, bnproj_b, qkvb, out);
}

// Round 21
// 444.809 us; speedup vs baseline: 1.0981x; 1.0722x over previous
//
#include <hip/hip_runtime.h>
#include <math.h>

#define S 16384      // 128*128 spatial
#define HW 128

typedef __attribute__((ext_vector_type(8))) short short8;
typedef __attribute__((ext_vector_type(4))) float f32x4;

__device__ __forceinline__ float mishf(float t) {
    float sp = (t > 20.0f) ? t : __logf(1.0f + __expf(t));
    float e2 = __expf(-2.0f * sp);
    return t * (1.0f - e2) * __builtin_amdgcn_rcpf(1.0f + e2);
}
__device__ __forceinline__ short f2bf(float f) {   // RNE f32 -> bf16 bits
    unsigned u = __float_as_uint(f);
    unsigned r = (u + 0x7FFFu + ((u >> 16) & 1u)) >> 16;
    return (short)r;
}
__device__ __forceinline__ float bf2f(short s) {
    unsigned u = ((unsigned)(unsigned short)s) << 16;
    return __uint_as_float(u);
}
__device__ __forceinline__ unsigned packhl(float v) {  // lo16=hi part, hi16=lo part
    short h = f2bf(v);
    short l = f2bf(v - bf2f(h));
    return (unsigned)(unsigned short)h | ((unsigned)(unsigned short)l << 16);
}
__device__ __forceinline__ void gl_lds16(const void* g, void* l) {
    __builtin_amdgcn_global_load_lds(
        (const __attribute__((address_space(1))) unsigned int*)g,
        (__attribute__((address_space(3))) unsigned int*)l, 16, 0, 0);
}
// swizzled LDS fragment read for [px][256B] rows
__device__ __forceinline__ short8 lds_frag(const char* base, int a) {
    int p = a ^ (((a >> 8) & 7) << 4);
    return *(const short8*)(base + p);
}
// swizzled LDS fragment read for [px][128B] rows
__device__ __forceinline__ short8 lds_frag128(const char* base, int a) {
    int p = a ^ (((a >> 7) & 7) << 4);
    return *(const short8*)(base + p);
}
__device__ __forceinline__ int swz128(int a) { return a ^ (((a >> 7) & 7) << 4); }
#define MFMA(a, b, c) __builtin_amdgcn_mfma_f32_16x16x32_bf16(a, b, c, 0, 0, 0)

// ---------------- prep: bf16 weights (2-term scheme) + zero t0p borders ----------------
__global__ void prep_kernel(const float* __restrict__ wq, const float* __restrict__ wk, const float* __restrict__ wv,
                            const float* __restrict__ bnq_s, const float* __restrict__ bnq_b,
                            const float* __restrict__ bnk_s, const float* __restrict__ bnk_b,
                            const float* __restrict__ bnv_s, const float* __restrict__ bnv_b,
                            const float* __restrict__ wpw, const float* __restrict__ wproj,
                            const float* __restrict__ wrow, const float* __restrict__ wcol,
                            const float* __restrict__ fc1_w, const float* __restrict__ wdw,
                            short* __restrict__ wqkv_h,
                            float* __restrict__ sqkv, float* __restrict__ bqkv,
                            short* __restrict__ wpw_h,
                            short* __restrict__ wproj_h,
                            float* __restrict__ wrowT, float* __restrict__ wcolT,
                            short* __restrict__ wch,
                            float* __restrict__ wdwT,
                            short* __restrict__ t0ph, short* __restrict__ t0pl) {
    int tid = blockIdx.x * 256 + threadIdx.x;
    if (tid < 256 * 128) {            // wqkv [oc 256][ic 128] bf16
        int oc = tid >> 7, ic = tid & 127;
        float w = (oc < 64) ? wq[oc * 128 + ic]
                : (oc < 128) ? wk[(oc - 64) * 128 + ic]
                : wv[(oc - 128) * 128 + ic];
        wqkv_h[tid] = f2bf(w);
    }
    if (tid < 256) {
        sqkv[tid] = (tid < 64) ? bnq_s[tid] : (tid < 128) ? bnk_s[tid - 64] : bnv_s[tid - 128];
        bqkv[tid] = (tid < 64) ? bnq_b[tid] : (tid < 128) ? bnk_b[tid - 64] : bnv_b[tid - 128];
    }
    if (tid < 128 * 256) {            // wpw [oc 128][ic 256] bf16
        wpw_h[tid] = f2bf(wpw[tid]);
    }
    if (tid < 128 * 128) {
        wproj_h[tid] = f2bf(wproj[tid]);   // [oc][ic]
        int ic = tid >> 7, oc = tid & 127;
        wrowT[tid] = wrow[oc * 128 + ic];
        wcolT[tid] = wcol[oc * 128 + ic];
    }
    if (tid < 9 * 128 * 128) {        // conv3x3 [tap][oc][ic] bf16
        int tap = tid >> 14;
        int oc = (tid >> 7) & 127;
        int ic = tid & 127;
        wch[tid] = f2bf(fc1_w[(oc * 128 + ic) * 9 + tap]);
    }
    if (tid < 9 * 256) {              // depthwise [tap][c]
        int tap = tid / 256, c = tid % 256;
        wdwT[tap * 256 + c] = wdw[c * 9 + tap];
    }
    if (tid < 132096) {               // border zero
        int bb = tid / 16512;
        int rem = tid - bb * 16512;
        int part = rem / 8256;
        int e = rem - part * 8256;
        short* p = part ? t0pl : t0ph;
        size_t ib = (size_t)bb * 130 * 130 * 128;
        short8 z = (short8){0, 0, 0, 0, 0, 0, 0, 0};
        if (e < 4160) {
            int row = (e < 2080) ? 0 : 129;
            int off = (e % 2080) * 8;
            *(short8*)(p + ib + (size_t)row * 130 * 128 + off) = z;
        } else {
            int e2 = e - 4160;
            int row = 1 + (e2 >> 5);
            int side = (e2 >> 4) & 1;
            int off = (e2 & 15) * 8;
            *(short8*)(p + ib + ((size_t)row * 130 + (side ? 129 : 0)) * 128 + off) = z;
        }
    }
}

// ---------------- pool (avg+max) + BN + Mish -> padded NHWC split bf16 ----------------
__global__ __launch_bounds__(256) void pool_kernel(const float* __restrict__ x,
                                                   const float* __restrict__ s1, const float* __restrict__ b1,
                                                   short* __restrict__ t0ph, short* __restrict__ t0pl) {
    __shared__ unsigned ot[64][132];
    int bx = blockIdx.x;               // 0..255
    int b = blockIdx.y;
    int h = bx >> 1, wh = bx & 1;
    int t = threadIdx.x;
    int wp = t & 31;                   // w-pair index (2 outputs each)
    int c8 = t >> 5;                   // 0..7
    int w0 = wh * 64 + wp * 2;
    for (int cs = 0; cs < 8; ++cs) {
        int c = cs * 8 + c8;           // 0..63
        const float* xp = x + (size_t)(b * 64 + c) * 65536;
        float vs[3][5], vm[3][5];
        #pragma unroll
        for (int kh = 0; kh < 3; ++kh) {
            int ih = 2 * h + kh - 1;
            bool hok = (unsigned)ih < 256u;
            #pragma unroll
            for (int j = 0; j < 5; ++j) {
                int iw = 2 * w0 - 1 + j;
                bool ok = hok && (unsigned)iw < 256u;
                float v = ok ? xp[ih * 256 + iw] : 0.f;
                vs[kh][j] = ok ? v : 0.f;
                vm[kh][j] = ok ? v : -INFINITY;
            }
        }
        #pragma unroll
        for (int o = 0; o < 2; ++o) {
            float sum = 0.f, mx = -INFINITY;
            #pragma unroll
            for (int kh = 0; kh < 3; ++kh)
                #pragma unroll
                for (int kw = 0; kw < 3; ++kw) {
                    sum += vs[kh][kw + 2 * o];
                    mx = fmaxf(mx, vm[kh][kw + 2 * o]);
                }
            float ta = mishf((sum * (1.f / 9.f)) * s1[c] + b1[c]);
            float tm = mishf(mx * s1[64 + c] + b1[64 + c]);
            ot[wp * 2 + o][c] = packhl(ta);
            ot[wp * 2 + o][64 + c] = packhl(tm);
        }
    }
    __syncthreads();
    size_t rowbase = ((size_t)(b * 130 + h + 1) * 130 + 1 + wh * 64) * 128;
    short* oph = t0ph + rowbase;
    short* opl = t0pl + rowbase;
    for (int idx = t; idx < 64 * 16; idx += 256) {
        int wloc = idx >> 4, co = idx & 15;
        short8 hv, lv;
        #pragma unroll
        for (int j = 0; j < 8; ++j) {
            unsigned u = ot[wloc][co * 8 + j];
            hv[j] = (short)(u & 0xFFFFu);
            lv[j] = (short)(u >> 16);
        }
        *(short8*)(oph + wloc * 128 + co * 8) = hv;
        *(short8*)(opl + wloc * 128 + co * 8) = lv;
    }
}

// ---------------- FUSED conv3x3 + qkv 1x1, 512 threads / 8 waves, 2-term split ----------------
// qkv output stored as plain bf16 NHWC (halves the biggest tensor's traffic).
__global__ __launch_bounds__(512) void convqkv_mfma(const short* __restrict__ t0ph,
                                                    const short* __restrict__ t0pl,
                                                    const short* __restrict__ wch,
                                                    const float* __restrict__ fb,
                                                    const short* __restrict__ wqkv_h,
                                                    const float* __restrict__ sc, const float* __restrict__ bi,
                                                    short* __restrict__ qh, float* __restrict__ rowmean) {
    __shared__ char sm[69632];          // staging 2x33792; reused as A-pack 2x[128][132]; rsum [2][256] at 67584
    char* smh = sm;
    char* sml = sm + 33792;
    float* rsum = (float*)(sm + 67584);
    int flat = blockIdx.x;              // 1024
    int b = flat & 7;                   // XCD-affine
    int h = flat >> 3;
    int tid = threadIdx.x, lane = tid & 63, wid = tid >> 6;
    int l15 = lane & 15, l4 = lane >> 4;
    int wrc = wid >> 2;                 // conv px half
    int wcc = wid & 3;                  // conv oc quarter (32 oc)
    int spbc = wrc * 64 + l15;
    int ocbc = wcc * 32 + l15;
    f32x4 acc[4][2];
    #pragma unroll
    for (int m = 0; m < 4; ++m)
        #pragma unroll
        for (int n = 0; n < 2; ++n) acc[m][n] = (f32x4){0.f, 0.f, 0.f, 0.f};
    for (int kh = 0; kh < 3; ++kh) {
        __syncthreads();
        const char* gh = (const char*)(t0ph + ((size_t)(b * 130 + h + kh) * 130) * 128);
        const char* gl = (const char*)(t0pl + ((size_t)(b * 130 + h + kh) * 130) * 128);
        #pragma unroll
        for (int it = 0; it < 5; ++it) {
            int idx = it * 512 + tid;           // 2080 x 16B per plane
            if (idx < 2080) {
                int dl = idx * 16;
                int srcoff = dl ^ (((dl >> 8) & 7) << 4);
                gl_lds16(gh + srcoff, smh + dl);
                gl_lds16(gl + srcoff, sml + dl);
            }
        }
        __syncthreads();
        #pragma unroll
        for (int kw = 0; kw < 3; ++kw) {
            const short* wbh = wch + (size_t)(kh * 3 + kw) * 16384;
            #pragma unroll
            for (int ks = 0; ks < 4; ++ks) {
                int kb = ks * 64 + l4 * 16;
                int kws = ks * 32 + l4 * 8;
                short8 ah[4], bh[2];
                #pragma unroll
                for (int m = 0; m < 4; ++m)
                    ah[m] = lds_frag(smh, ((spbc + m * 16 + kw) << 8) + kb);
                #pragma unroll
                for (int n = 0; n < 2; ++n)
                    bh[n] = *(const short8*)(wbh + (ocbc + n * 16) * 128 + kws);
                #pragma unroll
                for (int m = 0; m < 4; ++m)
                    #pragma unroll
                    for (int n = 0; n < 2; ++n)
                        acc[m][n] = MFMA(ah[m], bh[n], acc[m][n]);
                short8 al[4];
                #pragma unroll
                for (int m = 0; m < 4; ++m)
                    al[m] = lds_frag(sml, ((spbc + m * 16 + kw) << 8) + kb);
                #pragma unroll
                for (int m = 0; m < 4; ++m)
                    #pragma unroll
                    for (int n = 0; n < 2; ++n)
                        acc[m][n] = MFMA(al[m], bh[n], acc[m][n]);
                // 2-term: a_h*w_l dropped (weights bf16)
            }
        }
    }
    // pack conv output (y row) + bias into split-bf16 A tile in LDS
    float fbv[2];
    #pragma unroll
    for (int n = 0; n < 2; ++n) fbv[n] = fb[wcc * 32 + n * 16 + l15];
    rsum[tid] = 0.f;                    // 512 entries
    __syncthreads();
    short* ahi = (short*)sm;            // [128][132]
    short* alo = (short*)(sm + 33792);  // [128][132]
    #pragma unroll
    for (int m = 0; m < 4; ++m)
        #pragma unroll
        for (int n = 0; n < 2; ++n)
            #pragma unroll
            for (int r = 0; r < 4; ++r) {
                int px = wrc * 64 + m * 16 + l4 * 4 + r;
                int ocl = wcc * 32 + n * 16 + l15;
                unsigned u = packhl(acc[m][n][r] + fbv[n]);
                ahi[px * 132 + ocl] = (short)(u & 0xFFFFu);
                alo[px * 132 + ocl] = (short)(u >> 16);
            }
    __syncthreads();
    // qkv GEMM: A[128px][128ic] (LDS) x B[256oc][128ic], 8 waves, 2-term
    int spbq = wrc * 64 + l15;          // px half (reuse wrc)
    int ocbq = wcc * 64 + l15;          // oc quarter of 256 (64 oc)
    f32x4 aq[4][4];
    #pragma unroll
    for (int m = 0; m < 4; ++m)
        #pragma unroll
        for (int n = 0; n < 4; ++n) aq[m][n] = (f32x4){0.f, 0.f, 0.f, 0.f};
    #pragma unroll
    for (int ks = 0; ks < 4; ++ks) {
        int k0 = ks * 32 + l4 * 8;
        short8 ah[4], bh[4];
        #pragma unroll
        for (int m = 0; m < 4; ++m) ah[m] = *(const short8*)(ahi + (spbq + m * 16) * 132 + k0);
        #pragma unroll
        for (int n = 0; n < 4; ++n) bh[n] = *(const short8*)(wqkv_h + (size_t)(ocbq + n * 16) * 128 + k0);
        #pragma unroll
        for (int m = 0; m < 4; ++m)
            #pragma unroll
            for (int n = 0; n < 4; ++n) aq[m][n] = MFMA(ah[m], bh[n], aq[m][n]);
        short8 al[4];
        #pragma unroll
        for (int m = 0; m < 4; ++m) al[m] = *(const short8*)(alo + (spbq + m * 16) * 132 + k0);
        #pragma unroll
        for (int m = 0; m < 4; ++m)
            #pragma unroll
            for (int n = 0; n < 4; ++n) aq[m][n] = MFMA(al[m], bh[n], aq[m][n]);
        // 2-term: a_h*w_l dropped
    }
    // rowsum partials (raw acc; scale/bias at final store)
    #pragma unroll
    for (int n = 0; n < 4; ++n) {
        float v = 0.f;
        #pragma unroll
        for (int m = 0; m < 4; ++m)
            #pragma unroll
            for (int r = 0; r < 4; ++r) v += aq[m][n][r];
        v += __shfl_xor(v, 16);
        v += __shfl_xor(v, 32);
        if (l4 == 0) rsum[wrc * 256 + wcc * 64 + n * 16 + l15] = v;
    }
    // BN + bf16 store
    float s4[4], b4[4];
    #pragma unroll
    for (int n = 0; n < 4; ++n) {
        s4[n] = sc[wcc * 64 + n * 16 + l15];
        b4[n] = bi[wcc * 64 + n * 16 + l15];
    }
    short* rowout = qh + ((size_t)(b * 128 + h) * 128) * 256;
    #pragma unroll
    for (int m = 0; m < 4; ++m)
        #pragma unroll
        for (int n = 0; n < 4; ++n)
            #pragma unroll
            for (int r = 0; r < 4; ++r) {
                int px = wrc * 64 + m * 16 + l4 * 4 + r;
                int oc = wcc * 64 + n * 16 + l15;
                rowout[px * 256 + oc] = f2bf(aq[m][n][r] * s4[n] + b4[n]);
            }
    __syncthreads();
    if (tid < 256)
        rowmean[((size_t)b * 256 + tid) * 128 + h] =
            (rsum[tid] + rsum[256 + tid]) * sc[tid] * (1.f / 128.f) + bi[tid];
}

// ---------------- colmean: mean over h of qkv bf16 NHWC ----------------
__global__ __launch_bounds__(256) void colmean_kernel(const short* __restrict__ qh,
                                                      float* __restrict__ colmean) {
    __shared__ float red[8][256];
    int blk = blockIdx.x;                 // 1024
    int b = blk & 7, w = blk >> 3;        // XCD-affine
    int tid = threadIdx.x;
    int c8g = tid & 31;                   // channel group of 8
    int hs = tid >> 5;                    // 8 h-slices of 16
    float a8[8];
    #pragma unroll
    for (int k = 0; k < 8; ++k) a8[k] = 0.f;
    for (int j = 0; j < 16; ++j) {
        int h = hs * 16 + j;
        short8 v = *(const short8*)(qh + ((size_t)((b * 128 + h) * 128 + w)) * 256 + c8g * 8);
        #pragma unroll
        for (int k = 0; k < 8; ++k) a8[k] += bf2f(v[k]);
    }
    #pragma unroll
    for (int k = 0; k < 8; ++k) red[hs][c8g * 8 + k] = a8[k];
    __syncthreads();
    int c = tid;
    float s = 0.f;
    #pragma unroll
    for (int q = 0; q < 8; ++q) s += red[q][c];
    colmean[((size_t)b * 256 + c) * 128 + w] = s * (1.f / 128.f);
}

// ---------------- fused depthwise 3x3 + BN + ReLU + pointwise 256->128 MFMA + BN ----------------
__global__ __launch_bounds__(512) void dwpw_mfma(const short* __restrict__ qh,
                                                 const float* __restrict__ wdwT,
                                                 const float* __restrict__ ds, const float* __restrict__ db,
                                                 const short* __restrict__ wpw_h,
                                                 const float* __restrict__ sc, const float* __restrict__ bi,
                                                 float* __restrict__ qb) {
    __shared__ char sm[32768];
    char* smh = sm;           // dw out hi, [128w][128B] swizzled (64 c chunk)
    char* sml = sm + 16384;   // dw out lo
    int flat = blockIdx.x;
    int b = flat & 7, h = flat >> 3;
    int tid = threadIdx.x, lane = tid & 63, wid = tid >> 6;
    int wr = wid >> 2, wc = wid & 3;     // px half / oc quarter (32 oc)
    int l15 = lane & 15, l4 = lane >> 4;
    int spb = wr * 64 + l15;
    int ocb = wc * 32 + l15;
    int wdw_ = tid >> 3;      // 0..63 (w base, 2 w per thread)
    int c8t = tid & 7;        // c8 group within 64-c chunk
    f32x4 acc[4][2];
    #pragma unroll
    for (int m = 0; m < 4; ++m)
        #pragma unroll
        for (int n = 0; n < 2; ++n) acc[m][n] = (f32x4){0.f, 0.f, 0.f, 0.f};

    #pragma unroll 1
    for (int kc = 0; kc < 4; ++kc) {
        __syncthreads();      // previous chunk's MFMA reads done
        int cbase = kc * 64 + c8t * 8;
        #pragma unroll 1
        for (int i = 0; i < 2; ++i) {
            int w = wdw_ * 2 + i;
            float acc8[8];
            #pragma unroll
            for (int k = 0; k < 8; ++k) acc8[k] = 0.f;
            #pragma unroll
            for (int kh = 0; kh < 3; ++kh) {
                int ih = h + kh - 1;
                if ((unsigned)ih >= 128u) continue;
                #pragma unroll
                for (int kw = 0; kw < 3; ++kw) {
                    int iw = w + kw - 1;
                    if ((unsigned)iw >= 128u) continue;
                    short8 v = *(const short8*)(qh + ((size_t)((b * 128 + ih) * 128 + iw)) * 256 + cbase);
                    const float* wp = wdwT + (kh * 3 + kw) * 256 + cbase;
                    #pragma unroll
                    for (int k = 0; k < 8; ++k)
                        acc8[k] += wp[k] * bf2f(v[k]);
                }
            }
            short8 hv, lv;
            #pragma unroll
            for (int k = 0; k < 8; ++k) {
                float v = fmaxf(acc8[k] * ds[cbase + k] + db[cbase + k], 0.f);
                unsigned u = packhl(v);
                hv[k] = (short)(u & 0xFFFFu);
                lv[k] = (short)(u >> 16);
            }
            int a = swz128(w * 128 + c8t * 16);
            *(short8*)(smh + a) = hv;
            *(short8*)(sml + a) = lv;
        }
        __syncthreads();
        #pragma unroll
        for (int ks = 0; ks < 2; ++ks) {
            int kb = ks * 64 + l4 * 16;               // byte offset in 128B row
            int kws = kc * 64 + ks * 32 + l4 * 8;     // weight short offset (ic)
            short8 ah[4], bh[2];
            #pragma unroll
            for (int m = 0; m < 4; ++m) ah[m] = lds_frag128(smh, (spb + m * 16) * 128 + kb);
            #pragma unroll
            for (int n = 0; n < 2; ++n) bh[n] = *(const short8*)(wpw_h + (ocb + n * 16) * 256 + kws);
            #pragma unroll
            for (int m = 0; m < 4; ++m)
                #pragma unroll
                for (int n = 0; n < 2; ++n) acc[m][n] = MFMA(ah[m], bh[n], acc[m][n]);
            short8 al[4];
            #pragma unroll
            for (int m = 0; m < 4; ++m) al[m] = lds_frag128(sml, (spb + m * 16) * 128 + kb);
            #pragma unroll
            for (int m = 0; m < 4; ++m)
                #pragma unroll
                for (int n = 0; n < 2; ++n) acc[m][n] = MFMA(al[m], bh[n], acc[m][n]);
            // 2-term split
        }
    }
    float s4[2], b4[2];
    #pragma unroll
    for (int n = 0; n < 2; ++n) {
        s4[n] = sc[wc * 32 + n * 16 + l15];
        b4[n] = bi[wc * 32 + n * 16 + l15];
    }
    float* rowout = qb + ((size_t)(b * 128 + h) * 128) * 128;
    #pragma unroll
    for (int m = 0; m < 4; ++m)
        #pragma unroll
        for (int n = 0; n < 2; ++n)
            #pragma unroll
            for (int r = 0; r < 4; ++r) {
                int px = wr * 64 + m * 16 + l4 * 4 + r;
                int oc = wc * 32 + n * 16 + l15;
                rowout[px * 128 + oc] = acc[m][n][r] * s4[n] + b4[n];
            }
}

// ---------------- axial attention (row AND col in one launch) -> relu'd outputs ----------------
__global__ __launch_bounds__(128) void attn_kernel(const float* __restrict__ rowmean,
                                                   const float* __restrict__ colmean,
                                                   const float* __restrict__ pos_rq, const float* __restrict__ pos_rk,
                                                   const float* __restrict__ pos_cq, const float* __restrict__ pos_ck,
                                                   float* __restrict__ xr_act, float* __restrict__ xc_act) {
    __shared__ float qr[8][128], kr[8][128], vr[16][128];
    int iscol = blockIdx.x >> 6;
    int sub = blockIdx.x & 63;
    int b = sub >> 3, head = sub & 7;
    const float* meanbuf = iscol ? colmean : rowmean;
    const float* posq = iscol ? pos_cq : pos_rq;
    const float* posk = iscol ? pos_ck : pos_rk;
    float* xact = iscol ? xc_act : xr_act;
    int i = threadIdx.x;
    float src = (i + 0.5f) * 0.125f - 0.5f;
    src = fmaxf(src, 0.f);
    int i0 = (int)src;
    if (i0 > 15) i0 = 15;
    float f = src - (float)i0;
    int i1 = (i0 + 1 > 15) ? 15 : i0 + 1;
    const float* mb = meanbuf + (size_t)b * 256 * 128;
    for (int kd = 0; kd < 8; ++kd) {
        int cq = head * 8 + kd;
        qr[kd][i] = mb[cq * 128 + i] + posq[cq * 16 + i0] * (1.f - f) + posq[cq * 16 + i1] * f;
        kr[kd][i] = mb[(64 + cq) * 128 + i] + posk[cq * 16 + i0] * (1.f - f) + posk[cq * 16 + i1] * f;
    }
    for (int d = 0; d < 16; ++d)
        vr[d][i] = mb[(128 + head * 16 + d) * 128 + i];
    __syncthreads();
    float qreg[8];
    #pragma unroll
    for (int kd = 0; kd < 8; ++kd) qreg[kd] = qr[kd][i];
    const float scale = 0.35355339059327373f;
    float m = -INFINITY;
    for (int j = 0; j < 128; ++j) {
        float sj = 0.f;
        #pragma unroll
        for (int kd = 0; kd < 8; ++kd) sj += qreg[kd] * kr[kd][j];
        m = fmaxf(m, sj * scale);
    }
    float denom = 0.f;
    float acc[16];
    #pragma unroll
    for (int d = 0; d < 16; ++d) acc[d] = 0.f;
    for (int j = 0; j < 128; ++j) {
        float sj = 0.f;
        #pragma unroll
        for (int kd = 0; kd < 8; ++kd) sj += qreg[kd] * kr[kd][j];
        float pj = __expf(sj * scale - m);
        denom += pj;
        #pragma unroll
        for (int d = 0; d < 16; ++d) acc[d] += pj * vr[d][j];
    }
    float inv = __builtin_amdgcn_rcpf(denom);
    float* xp = xact + ((size_t)b * 128 + head * 16) * 128;
    for (int d = 0; d < 16; ++d)
        xp[d * 128 + i] = fmaxf(acc[d] * inv, 0.f);
}

// ---------------- 1x1 conv on xr/xc + BN -> TRANSPOSED [b][i][ic] outputs ----------------
__global__ __launch_bounds__(256) void rc_conv_kernel(const float* __restrict__ xr_act, const float* __restrict__ xc_act,
                                                      const float* __restrict__ wrowT, const float* __restrict__ wcolT,
                                                      const float* __restrict__ rs, const float* __restrict__ rb,
                                                      const float* __restrict__ cs, const float* __restrict__ cb,
                                                      float* __restrict__ xrT, float* __restrict__ xcT) {
    __shared__ float4 lds[128][16];
    int blk = blockIdx.x;             // 0..31
    int iscol = blk >> 4;
    int rem = blk & 15;
    int b = rem >> 1;
    int i0 = (rem & 1) * 64;
    const float* src = iscol ? xc_act : xr_act;
    const float* wT  = iscol ? wcolT : wrowT;
    const float* ss  = iscol ? cs : rs;
    const float* sb  = iscol ? cb : rb;
    float* dst       = iscol ? xcT : xrT;
    int tid = threadIdx.x;
    const float4* src4 = (const float4*)(src + (size_t)b * 16384 + i0);
    for (int idx = tid; idx < 128 * 16; idx += 256) {
        int ic = idx >> 4, q = idx & 15;
        lds[ic][q] = src4[ic * 32 + q];
    }
    __syncthreads();
    int oc = tid & 127, sub = tid >> 7;
    float4 acc[8];
    #pragma unroll
    for (int q = 0; q < 8; ++q) acc[q] = make_float4(0.f, 0.f, 0.f, 0.f);
    for (int ic = 0; ic < 128; ++ic) {
        float w = wT[ic * 128 + oc];
        #pragma unroll
        for (int q = 0; q < 8; ++q) {
            float4 v = lds[ic][sub * 8 + q];
            acc[q].x += w * v.x; acc[q].y += w * v.y;
            acc[q].z += w * v.z; acc[q].w += w * v.w;
        }
    }
    float s = ss[oc], bb = sb[oc];
    int ibase = i0 + sub * 32;
    #pragma unroll
    for (int q = 0; q < 8; ++q) {
        float vv[4] = {acc[q].x, acc[q].y, acc[q].z, acc[q].w};
        #pragma unroll
        for (int r = 0; r < 4; ++r) {
            int i = ibase + q * 4 + r;
            dst[((size_t)b * 128 + i) * 128 + oc] = vv[r] * s + bb;
        }
    }
}

// ---------------- final: xx=v+xr+xc, relu, proj MFMA + BN, hsig*qkv_b -> out NCHW ----------------
__global__ __launch_bounds__(512) void final_mfma(const short* __restrict__ qh,
                                                  const float* __restrict__ xrT, const float* __restrict__ xcT,
                                                  const short* __restrict__ wproj_h,
                                                  const float* __restrict__ ps, const float* __restrict__ pb,
                                                  const float* __restrict__ qb, float* __restrict__ out) {
    __shared__ char sm[69632];
    short* ahi = (short*)sm;              // [128][136]
    short* alo = (short*)(sm + 34816);    // [128][136]
    int flat = blockIdx.x;
    int b = flat & 7, h = flat >> 3;
    int tid = threadIdx.x, lane = tid & 63, wid = tid >> 6;
    int wr = wid >> 2, wc = wid & 3;      // px half / oc quarter (32 oc)
    int l15 = lane & 15, l4 = lane >> 4;
    int spb = wr * 64 + l15;
    int ocb = wc * 32 + l15;
    for (int i = 0; i < 4; ++i) {
        int idx = tid + i * 512;          // 2048 = 128px x 16 groups
        int px = idx >> 4, g = idx & 15;
        short8 v8 = *(const short8*)(qh + ((size_t)((b * 128 + h) * 128 + px)) * 256 + 128 + g * 8);
        const float* xr = xrT + ((size_t)(b * 128 + h)) * 128 + g * 8;
        const float* xc = xcT + ((size_t)(b * 128 + px)) * 128 + g * 8;
        short8 hv, lv;
        #pragma unroll
        for (int k = 0; k < 8; ++k) {
            float v = bf2f(v8[k]) + xr[k] + xc[k];
            v = fmaxf(v, 0.f);
            unsigned u = packhl(v);
            hv[k] = (short)(u & 0xFFFFu);
            lv[k] = (short)(u >> 16);
        }
        *(short8*)(ahi + px * 136 + g * 8) = hv;
        *(short8*)(alo + px * 136 + g * 8) = lv;
    }
    __syncthreads();
    f32x4 acc[4][2];
    #pragma unroll
    for (int m = 0; m < 4; ++m)
        #pragma unroll
        for (int n = 0; n < 2; ++n) acc[m][n] = (f32x4){0.f, 0.f, 0.f, 0.f};
    #pragma unroll
    for (int ks = 0; ks < 4; ++ks) {
        int ko = ks * 32 + l4 * 8;
        short8 ah[4], bh[2];
        #pragma unroll
        for (int m = 0; m < 4; ++m) ah[m] = *(const short8*)(ahi + (spb + m * 16) * 136 + ko);
        #pragma unroll
        for (int n = 0; n < 2; ++n) bh[n] = *(const short8*)(wproj_h + (ocb + n * 16) * 128 + ko);
        #pragma unroll
        for (int m = 0; m < 4; ++m)
            #pragma unroll
            for (int n = 0; n < 2; ++n) acc[m][n] = MFMA(ah[m], bh[n], acc[m][n]);
        short8 al[4];
        #pragma unroll
        for (int m = 0; m < 4; ++m) al[m] = *(const short8*)(alo + (spb + m * 16) * 136 + ko);
        #pragma unroll
        for (int m = 0; m < 4; ++m)
            #pragma unroll
            for (int n = 0; n < 2; ++n) acc[m][n] = MFMA(al[m], bh[n], acc[m][n]);
        // 2-term split
    }
    float s4[2], b4[2];
    #pragma unroll
    for (int n = 0; n < 2; ++n) {
        s4[n] = ps[wc * 32 + n * 16 + l15];
        b4[n] = pb[wc * 32 + n * 16 + l15];
    }
    float* tr = (float*)sm;    // [64 ocl][129 px]
    #pragma unroll 1
    for (int p = 0; p < 2; ++p) {
        __syncthreads();
        if ((wc >> 1) == p) {
            #pragma unroll
            for (int n = 0; n < 2; ++n)
                #pragma unroll
                for (int m = 0; m < 4; ++m)
                    #pragma unroll
                    for (int r = 0; r < 4; ++r) {
                        int px = wr * 64 + m * 16 + l4 * 4 + r;
                        int ocl = (wc & 1) * 32 + n * 16 + l15;    // 0..63 within half
                        int oc = p * 64 + ocl;
                        float val = acc[m][n][r] * s4[n] + b4[n];
                        float hs = fminf(fmaxf(val + 3.f, 0.f), 6.f) * (1.f / 6.f);
                        float g = qb[((size_t)((b * 128 + h) * 128 + px)) * 128 + oc];
                        tr[ocl * 129 + px] = hs * g;
                    }
        }
        __syncthreads();
        int ocl = tid >> 3, q = tid & 7;      // 64 ocl x 8 q
        int oc = p * 64 + ocl;
        float* yp = out + (size_t)(b * 128 + oc) * S + h * 128 + q * 16;
        #pragma unroll
        for (int j = 0; j < 16; j += 4) {
            float4 v;
            v.x = tr[ocl * 129 + q * 16 + j];
            v.y = tr[ocl * 129 + q * 16 + j + 1];
            v.z = tr[ocl * 129 + q * 16 + j + 2];
            v.w = tr[ocl * 129 + q * 16 + j + 3];
            *(float4*)(yp + j) = v;
        }
    }
}

extern "C" void kernel_launch(void* const* d_in, const int* in_sizes, int n_in,
                              void* d_out, int out_size, void* d_ws, size_t ws_size,
                              hipStream_t stream) {
    const float* x       = (const float*)d_in[0];
    const float* bn1_s   = (const float*)d_in[1];
    const float* bn1_b   = (const float*)d_in[2];
    const float* fc1_w   = (const float*)d_in[3];
    const float* fc1_b   = (const float*)d_in[4];
    const float* wq      = (const float*)d_in[5];
    const float* bnq_s   = (const float*)d_in[6];
    const float* bnq_b   = (const float*)d_in[7];
    const float* wk      = (const float*)d_in[8];
    const float* bnk_s   = (const float*)d_in[9];
    const float* bnk_b   = (const float*)d_in[10];
    const float* wv      = (const float*)d_in[11];
    const float* bnv_s   = (const float*)d_in[12];
    const float* bnv_b   = (const float*)d_in[13];
    const float* pos_rq  = (const float*)d_in[14];
    const float* pos_rk  = (const float*)d_in[15];
    const float* pos_cq  = (const float*)d_in[16];
    const float* pos_ck  = (const float*)d_in[17];
    const float* wrow    = (const float*)d_in[18];
    const float* bnrow_s = (const float*)d_in[19];
    const float* bnrow_b = (const float*)d_in[20];
    const float* wcol    = (const float*)d_in[21];
    const float* bncol_s = (const float*)d_in[22];
    const float* bncol_b = (const float*)d_in[23];
    const float* wproj   = (const float*)d_in[24];
    const float* bnproj_s= (const float*)d_in[25];
    const float* bnproj_b= (const float*)d_in[26];
    const float* wdw     = (const float*)d_in[27];
    const float* bndw_s  = (const float*)d_in[28];
    const float* bndw_b  = (const float*)d_in[29];
    const float* wpw     = (const float*)d_in[30];
    const float* bnpw_s  = (const float*)d_in[31];
    const float* bnpw_b  = (const float*)d_in[32];

    char* ws = (char*)d_ws;
    short* t0ph  = (short*)(ws);                        // 34,611,200  [8][130][130][128]
    short* t0pl  = (short*)(ws + (size_t)34611200);     // 34,611,200
    short* qkvh  = (short*)(ws + (size_t)136331264);    // 67,108,864  [8][128][128][256] bf16
    float* qkvb  = (float*)(ws + (size_t)270548992);    // 67,108,864  [8][128][128][128] f32
    char* sp = ws + (size_t)337657856;
    float* rowmean = (float*)sp; sp += 1048576;
    float* colmean = (float*)sp; sp += 1048576;
    float* xr_act  = (float*)sp; sp += 524288;
    float* xc_act  = (float*)sp; sp += 524288;
    float* xrT     = (float*)sp; sp += 524288;
    float* xcT     = (float*)sp; sp += 524288;
    short* wch     = (short*)sp; sp += 294912;
    short* wqkv_h  = (short*)sp; sp += 65536;
    short* wpw_h   = (short*)sp; sp += 65536;
    short* wproj_h = (short*)sp; sp += 32768;
    float* wrowT   = (float*)sp; sp += 65536;
    float* wcolT   = (float*)sp; sp += 65536;
    float* sqkv    = (float*)sp; sp += 1024;
    float* bqkv    = (float*)sp; sp += 1024;
    float* wdwT    = (float*)sp; sp += 9216;

    float* out = (float*)d_out;

    prep_kernel<<<576, 256, 0, stream>>>(wq, wk, wv, bnq_s, bnq_b, bnk_s, bnk_b, bnv_s, bnv_b,
                                         wpw, wproj, wrow, wcol, fc1_w, wdw,
                                         wqkv_h, sqkv, bqkv, wpw_h,
                                         wproj_h, wrowT, wcolT, wch, wdwT,
                                         t0ph, t0pl);
    pool_kernel<<<dim3(256, 8), 256, 0, stream>>>(x, bn1_s, bn1_b, t0ph, t0pl);
    convqkv_mfma<<<1024, 512, 0, stream>>>(t0ph, t0pl, wch, fc1_b,
                                           wqkv_h, sqkv, bqkv, qkvh, rowmean);
    colmean_kernel<<<1024, 256, 0, stream>>>(qkvh, colmean);
    dwpw_mfma<<<1024, 512, 0, stream>>>(qkvh, wdwT, bndw_s, bndw_b,
                                        wpw_h, bnpw_s, bnpw_b, qkvb);
    attn_kernel<<<128, 128, 0, stream>>>(rowmean, colmean, pos_rq, pos_rk, pos_cq, pos_ck,
                                         xr_act, xc_act);
    rc_conv_kernel<<<32, 256, 0, stream>>>(xr_act, xc_act, wrowT, wcolT,
                                           bnrow_s, bnrow_b, bncol_s, bncol_b, xrT, xcT);
    final_mfma<<<1024, 512, 0, stream>>>(qkvh, xrT, xcT, wproj_h,
                                         bnproj_s, bnproj_b, qkvb, out);
}

// Round 22
// 391.224 us; speedup vs baseline: 1.2485x; 1.1370x over previous
//
#include <hip/hip_runtime.h>
#include <math.h>

#define S 16384      // 128*128 spatial
#define HW 128

typedef __attribute__((ext_vector_type(8))) short short8;
typedef __attribute__((ext_vector_type(8))) _Float16 half8;
typedef __attribute__((ext_vector_type(4))) float f32x4;

__device__ __forceinline__ float mishf(float t) {
    float sp = (t > 20.0f) ? t : __logf(1.0f + __expf(t));
    float e2 = __expf(-2.0f * sp);
    return t * (1.0f - e2) * __builtin_amdgcn_rcpf(1.0f + e2);
}
__device__ __forceinline__ short f2h(float f) {   // RNE f32 -> fp16 bits
    _Float16 h = (_Float16)f;
    return __builtin_bit_cast(short, h);
}
__device__ __forceinline__ void gl_lds16(const void* g, void* l) {
    __builtin_amdgcn_global_load_lds(
        (const __attribute__((address_space(1))) unsigned int*)g,
        (__attribute__((address_space(3))) unsigned int*)l, 16, 0, 0);
}
// swizzled LDS fragment read for [px][256B] rows
__device__ __forceinline__ half8 lds_fragh(const char* base, int a) {
    int p = a ^ (((a >> 8) & 7) << 4);
    return *(const half8*)(base + p);
}
// swizzled LDS fragment read for [px][128B] rows
__device__ __forceinline__ half8 lds_frag128h(const char* base, int a) {
    int p = a ^ (((a >> 7) & 7) << 4);
    return *(const half8*)(base + p);
}
__device__ __forceinline__ int swz128(int a) { return a ^ (((a >> 7) & 7) << 4); }
#define MFMA(a, b, c) __builtin_amdgcn_mfma_f32_16x16x32_f16(a, b, c, 0, 0, 0)

// ---------------- prep: fp16 weights + zero t0p borders ----------------
__global__ void prep_kernel(const float* __restrict__ wq, const float* __restrict__ wk, const float* __restrict__ wv,
                            const float* __restrict__ bnq_s, const float* __restrict__ bnq_b,
                            const float* __restrict__ bnk_s, const float* __restrict__ bnk_b,
                            const float* __restrict__ bnv_s, const float* __restrict__ bnv_b,
                            const float* __restrict__ wpw, const float* __restrict__ wproj,
                            const float* __restrict__ wrow, const float* __restrict__ wcol,
                            const float* __restrict__ fc1_w, const float* __restrict__ wdw,
                            short* __restrict__ wqkv_h,
                            float* __restrict__ sqkv, float* __restrict__ bqkv,
                            short* __restrict__ wpw_h,
                            short* __restrict__ wproj_h,
                            float* __restrict__ wrowT, float* __restrict__ wcolT,
                            short* __restrict__ wch,
                            float* __restrict__ wdwT,
                            short* __restrict__ t0p) {
    int tid = blockIdx.x * 256 + threadIdx.x;
    if (tid < 256 * 128) {            // wqkv [oc 256][ic 128] fp16
        int oc = tid >> 7, ic = tid & 127;
        float w = (oc < 64) ? wq[oc * 128 + ic]
                : (oc < 128) ? wk[(oc - 64) * 128 + ic]
                : wv[(oc - 128) * 128 + ic];
        wqkv_h[tid] = f2h(w);
    }
    if (tid < 256) {
        sqkv[tid] = (tid < 64) ? bnq_s[tid] : (tid < 128) ? bnk_s[tid - 64] : bnv_s[tid - 128];
        bqkv[tid] = (tid < 64) ? bnq_b[tid] : (tid < 128) ? bnk_b[tid - 64] : bnv_b[tid - 128];
    }
    if (tid < 128 * 256) {            // wpw [oc 128][ic 256] fp16
        wpw_h[tid] = f2h(wpw[tid]);
    }
    if (tid < 128 * 128) {
        wproj_h[tid] = f2h(wproj[tid]);   // [oc][ic]
        int ic = tid >> 7, oc = tid & 127;
        wrowT[tid] = wrow[oc * 128 + ic];
        wcolT[tid] = wcol[oc * 128 + ic];
    }
    if (tid < 9 * 128 * 128) {        // conv3x3 [tap][oc][ic] fp16
        int tap = tid >> 14;
        int oc = (tid >> 7) & 127;
        int ic = tid & 127;
        wch[tid] = f2h(fc1_w[(oc * 128 + ic) * 9 + tap]);
    }
    if (tid < 9 * 256) {              // depthwise [tap][c]
        int tap = tid / 256, c = tid % 256;
        wdwT[tap * 256 + c] = wdw[c * 9 + tap];
    }
    if (tid < 66048) {                // border zero (single plane)
        int bb = tid / 8256;
        int e = tid - bb * 8256;
        size_t ib = (size_t)bb * 130 * 130 * 128;
        short8 z = (short8){0, 0, 0, 0, 0, 0, 0, 0};
        if (e < 4160) {
            int row = (e < 2080) ? 0 : 129;
            int off = (e % 2080) * 8;
            *(short8*)(t0p + ib + (size_t)row * 130 * 128 + off) = z;
        } else {
            int e2 = e - 4160;
            int row = 1 + (e2 >> 5);
            int side = (e2 >> 4) & 1;
            int off = (e2 & 15) * 8;
            *(short8*)(t0p + ib + ((size_t)row * 130 + (side ? 129 : 0)) * 128 + off) = z;
        }
    }
}

// ---------------- pool (avg+max) + BN + Mish -> padded NHWC fp16 ----------------
__global__ __launch_bounds__(256) void pool_kernel(const float* __restrict__ x,
                                                   const float* __restrict__ s1, const float* __restrict__ b1,
                                                   short* __restrict__ t0p) {
    __shared__ short ot[64][136];
    int bx = blockIdx.x;               // 0..255
    int b = blockIdx.y;
    int h = bx >> 1, wh = bx & 1;
    int t = threadIdx.x;
    int wp = t & 31;                   // w-pair index (2 outputs each)
    int c8 = t >> 5;                   // 0..7
    int w0 = wh * 64 + wp * 2;
    for (int cs = 0; cs < 8; ++cs) {
        int c = cs * 8 + c8;           // 0..63
        const float* xp = x + (size_t)(b * 64 + c) * 65536;
        float vs[3][5], vm[3][5];
        #pragma unroll
        for (int kh = 0; kh < 3; ++kh) {
            int ih = 2 * h + kh - 1;
            bool hok = (unsigned)ih < 256u;
            #pragma unroll
            for (int j = 0; j < 5; ++j) {
                int iw = 2 * w0 - 1 + j;
                bool ok = hok && (unsigned)iw < 256u;
                float v = ok ? xp[ih * 256 + iw] : 0.f;
                vs[kh][j] = ok ? v : 0.f;
                vm[kh][j] = ok ? v : -INFINITY;
            }
        }
        #pragma unroll
        for (int o = 0; o < 2; ++o) {
            float sum = 0.f, mx = -INFINITY;
            #pragma unroll
            for (int kh = 0; kh < 3; ++kh)
                #pragma unroll
                for (int kw = 0; kw < 3; ++kw) {
                    sum += vs[kh][kw + 2 * o];
                    mx = fmaxf(mx, vm[kh][kw + 2 * o]);
                }
            float ta = mishf((sum * (1.f / 9.f)) * s1[c] + b1[c]);
            float tm = mishf(mx * s1[64 + c] + b1[64 + c]);
            ot[wp * 2 + o][c] = f2h(ta);
            ot[wp * 2 + o][64 + c] = f2h(tm);
        }
    }
    __syncthreads();
    size_t rowbase = ((size_t)(b * 130 + h + 1) * 130 + 1 + wh * 64) * 128;
    short* op = t0p + rowbase;
    for (int idx = t; idx < 64 * 16; idx += 256) {
        int wloc = idx >> 4, co = idx & 15;
        short8 v = *(const short8*)(&ot[wloc][co * 8]);
        *(short8*)(op + wloc * 128 + co * 8) = v;
    }
}

// ---------------- FUSED conv3x3 + qkv 1x1, 512 threads / 8 waves, fp16 single-term ----------------
// LDS: staging [33280] reused as A-pack [128][132] fp16; rsum f32[512] at 33792.
__global__ __launch_bounds__(512) void convqkv_mfma(const short* __restrict__ t0p,
                                                    const short* __restrict__ wch,
                                                    const float* __restrict__ fb,
                                                    const short* __restrict__ wqkv_h,
                                                    const float* __restrict__ sc, const float* __restrict__ bi,
                                                    short* __restrict__ qh, float* __restrict__ rowmean) {
    __shared__ char sm[35840];
    float* rsum = (float*)(sm + 33792);
    int flat = blockIdx.x;              // 1024
    int b = flat & 7;                   // XCD-affine
    int h = flat >> 3;
    int tid = threadIdx.x, lane = tid & 63, wid = tid >> 6;
    int l15 = lane & 15, l4 = lane >> 4;
    int wrc = wid >> 2;                 // conv px half
    int wcc = wid & 3;                  // conv oc quarter (32 oc)
    int spbc = wrc * 64 + l15;
    int ocbc = wcc * 32 + l15;
    f32x4 acc[4][2];
    #pragma unroll
    for (int m = 0; m < 4; ++m)
        #pragma unroll
        for (int n = 0; n < 2; ++n) acc[m][n] = (f32x4){0.f, 0.f, 0.f, 0.f};
    for (int kh = 0; kh < 3; ++kh) {
        __syncthreads();
        const char* gp = (const char*)(t0p + ((size_t)(b * 130 + h + kh) * 130) * 128);
        #pragma unroll
        for (int it = 0; it < 5; ++it) {
            int idx = it * 512 + tid;           // 2080 x 16B
            if (idx < 2080) {
                int dl = idx * 16;
                int srcoff = dl ^ (((dl >> 8) & 7) << 4);
                gl_lds16(gp + srcoff, sm + dl);
            }
        }
        __syncthreads();
        #pragma unroll
        for (int kw = 0; kw < 3; ++kw) {
            const short* wbh = wch + (size_t)(kh * 3 + kw) * 16384;
            #pragma unroll
            for (int ks = 0; ks < 4; ++ks) {
                int kb = ks * 64 + l4 * 16;
                int kws = ks * 32 + l4 * 8;
                half8 ah[4], bh[2];
                #pragma unroll
                for (int m = 0; m < 4; ++m)
                    ah[m] = lds_fragh(sm, ((spbc + m * 16 + kw) << 8) + kb);
                #pragma unroll
                for (int n = 0; n < 2; ++n)
                    bh[n] = *(const half8*)(wbh + (ocbc + n * 16) * 128 + kws);
                #pragma unroll
                for (int m = 0; m < 4; ++m)
                    #pragma unroll
                    for (int n = 0; n < 2; ++n)
                        acc[m][n] = MFMA(ah[m], bh[n], acc[m][n]);
            }
        }
    }
    // pack conv output (y row) + bias into fp16 A tile in LDS (reuse staging region)
    float fbv[2];
    #pragma unroll
    for (int n = 0; n < 2; ++n) fbv[n] = fb[wcc * 32 + n * 16 + l15];
    rsum[tid] = 0.f;                    // 512 entries
    __syncthreads();
    short* ap = (short*)sm;             // [128][132]
    #pragma unroll
    for (int m = 0; m < 4; ++m)
        #pragma unroll
        for (int n = 0; n < 2; ++n)
            #pragma unroll
            for (int r = 0; r < 4; ++r) {
                int px = wrc * 64 + m * 16 + l4 * 4 + r;
                int ocl = wcc * 32 + n * 16 + l15;
                ap[px * 132 + ocl] = f2h(acc[m][n][r] + fbv[n]);
            }
    __syncthreads();
    // qkv GEMM: A[128px][128ic] (LDS fp16) x B[256oc][128ic] fp16, 8 waves
    int spbq = wrc * 64 + l15;          // px half
    int ocbq = wcc * 64 + l15;          // oc quarter of 256 (64 oc)
    f32x4 aq[4][4];
    #pragma unroll
    for (int m = 0; m < 4; ++m)
        #pragma unroll
        for (int n = 0; n < 4; ++n) aq[m][n] = (f32x4){0.f, 0.f, 0.f, 0.f};
    #pragma unroll
    for (int ks = 0; ks < 4; ++ks) {
        int k0 = ks * 32 + l4 * 8;
        half8 ah[4], bh[4];
        #pragma unroll
        for (int m = 0; m < 4; ++m) ah[m] = *(const half8*)(ap + (spbq + m * 16) * 132 + k0);
        #pragma unroll
        for (int n = 0; n < 4; ++n) bh[n] = *(const half8*)(wqkv_h + (size_t)(ocbq + n * 16) * 128 + k0);
        #pragma unroll
        for (int m = 0; m < 4; ++m)
            #pragma unroll
            for (int n = 0; n < 4; ++n) aq[m][n] = MFMA(ah[m], bh[n], aq[m][n]);
    }
    // rowsum partials (raw acc; scale/bias at final store)
    #pragma unroll
    for (int n = 0; n < 4; ++n) {
        float v = 0.f;
        #pragma unroll
        for (int m = 0; m < 4; ++m)
            #pragma unroll
            for (int r = 0; r < 4; ++r) v += aq[m][n][r];
        v += __shfl_xor(v, 16);
        v += __shfl_xor(v, 32);
        if (l4 == 0) rsum[wrc * 256 + wcc * 64 + n * 16 + l15] = v;
    }
    // BN + fp16 store
    float s4[4], b4[4];
    #pragma unroll
    for (int n = 0; n < 4; ++n) {
        s4[n] = sc[wcc * 64 + n * 16 + l15];
        b4[n] = bi[wcc * 64 + n * 16 + l15];
    }
    short* rowout = qh + ((size_t)(b * 128 + h) * 128) * 256;
    #pragma unroll
    for (int m = 0; m < 4; ++m)
        #pragma unroll
        for (int n = 0; n < 4; ++n)
            #pragma unroll
            for (int r = 0; r < 4; ++r) {
                int px = wrc * 64 + m * 16 + l4 * 4 + r;
                int oc = wcc * 64 + n * 16 + l15;
                rowout[px * 256 + oc] = f2h(aq[m][n][r] * s4[n] + b4[n]);
            }
    __syncthreads();
    if (tid < 256)
        rowmean[((size_t)b * 256 + tid) * 128 + h] =
            (rsum[tid] + rsum[256 + tid]) * sc[tid] * (1.f / 128.f) + bi[tid];
}

// ---------------- colmean: mean over h of qkv fp16 NHWC ----------------
__global__ __launch_bounds__(256) void colmean_kernel(const short* __restrict__ qh,
                                                      float* __restrict__ colmean) {
    __shared__ float red[8][256];
    int blk = blockIdx.x;                 // 1024
    int b = blk & 7, w = blk >> 3;        // XCD-affine
    int tid = threadIdx.x;
    int c8g = tid & 31;                   // channel group of 8
    int hs = tid >> 5;                    // 8 h-slices of 16
    float a8[8];
    #pragma unroll
    for (int k = 0; k < 8; ++k) a8[k] = 0.f;
    for (int j = 0; j < 16; ++j) {
        int h = hs * 16 + j;
        half8 v = *(const half8*)(qh + ((size_t)((b * 128 + h) * 128 + w)) * 256 + c8g * 8);
        #pragma unroll
        for (int k = 0; k < 8; ++k) a8[k] += (float)v[k];
    }
    #pragma unroll
    for (int k = 0; k < 8; ++k) red[hs][c8g * 8 + k] = a8[k];
    __syncthreads();
    int c = tid;
    float s = 0.f;
    #pragma unroll
    for (int q = 0; q < 8; ++q) s += red[q][c];
    colmean[((size_t)b * 256 + c) * 128 + w] = s * (1.f / 128.f);
}

// ---------------- fused depthwise 3x3 + BN + ReLU + pointwise 256->128 fp16 MFMA + BN ----------------
__global__ __launch_bounds__(512) void dwpw_mfma(const short* __restrict__ qh,
                                                 const float* __restrict__ wdwT,
                                                 const float* __restrict__ ds, const float* __restrict__ db,
                                                 const short* __restrict__ wpw_h,
                                                 const float* __restrict__ sc, const float* __restrict__ bi,
                                                 float* __restrict__ qb) {
    __shared__ char sm[16384];           // dw out fp16, [128w][128B] swizzled (64 c chunk)
    int flat = blockIdx.x;
    int b = flat & 7, h = flat >> 3;
    int tid = threadIdx.x, lane = tid & 63, wid = tid >> 6;
    int wr = wid >> 2, wc = wid & 3;     // px half / oc quarter (32 oc)
    int l15 = lane & 15, l4 = lane >> 4;
    int spb = wr * 64 + l15;
    int ocb = wc * 32 + l15;
    int wdw_ = tid >> 3;      // 0..63 (w base, 2 w per thread)
    int c8t = tid & 7;        // c8 group within 64-c chunk
    f32x4 acc[4][2];
    #pragma unroll
    for (int m = 0; m < 4; ++m)
        #pragma unroll
        for (int n = 0; n < 2; ++n) acc[m][n] = (f32x4){0.f, 0.f, 0.f, 0.f};

    #pragma unroll 1
    for (int kc = 0; kc < 4; ++kc) {
        __syncthreads();      // previous chunk's MFMA reads done
        int cbase = kc * 64 + c8t * 8;
        #pragma unroll 1
        for (int i = 0; i < 2; ++i) {
            int w = wdw_ * 2 + i;
            float acc8[8];
            #pragma unroll
            for (int k = 0; k < 8; ++k) acc8[k] = 0.f;
            #pragma unroll
            for (int kh = 0; kh < 3; ++kh) {
                int ih = h + kh - 1;
                if ((unsigned)ih >= 128u) continue;
                #pragma unroll
                for (int kw = 0; kw < 3; ++kw) {
                    int iw = w + kw - 1;
                    if ((unsigned)iw >= 128u) continue;
                    half8 v = *(const half8*)(qh + ((size_t)((b * 128 + ih) * 128 + iw)) * 256 + cbase);
                    const float* wp = wdwT + (kh * 3 + kw) * 256 + cbase;
                    #pragma unroll
                    for (int k = 0; k < 8; ++k)
                        acc8[k] += wp[k] * (float)v[k];
                }
            }
            short8 hv;
            #pragma unroll
            for (int k = 0; k < 8; ++k) {
                float v = fmaxf(acc8[k] * ds[cbase + k] + db[cbase + k], 0.f);
                hv[k] = f2h(v);
            }
            *(short8*)(sm + swz128(w * 128 + c8t * 16)) = hv;
        }
        __syncthreads();
        #pragma unroll
        for (int ks = 0; ks < 2; ++ks) {
            int kb = ks * 64 + l4 * 16;               // byte offset in 128B row
            int kws = kc * 64 + ks * 32 + l4 * 8;     // weight short offset (ic)
            half8 ah[4], bh[2];
            #pragma unroll
            for (int m = 0; m < 4; ++m) ah[m] = lds_frag128h(sm, (spb + m * 16) * 128 + kb);
            #pragma unroll
            for (int n = 0; n < 2; ++n) bh[n] = *(const half8*)(wpw_h + (ocb + n * 16) * 256 + kws);
            #pragma unroll
            for (int m = 0; m < 4; ++m)
                #pragma unroll
                for (int n = 0; n < 2; ++n) acc[m][n] = MFMA(ah[m], bh[n], acc[m][n]);
        }
    }
    float s4[2], b4[2];
    #pragma unroll
    for (int n = 0; n < 2; ++n) {
        s4[n] = sc[wc * 32 + n * 16 + l15];
        b4[n] = bi[wc * 32 + n * 16 + l15];
    }
    float* rowout = qb + ((size_t)(b * 128 + h) * 128) * 128;
    #pragma unroll
    for (int m = 0; m < 4; ++m)
        #pragma unroll
        for (int n = 0; n < 2; ++n)
            #pragma unroll
            for (int r = 0; r < 4; ++r) {
                int px = wr * 64 + m * 16 + l4 * 4 + r;
                int oc = wc * 32 + n * 16 + l15;
                rowout[px * 128 + oc] = acc[m][n][r] * s4[n] + b4[n];
            }
}

// ---------------- axial attention (row AND col in one launch) -> relu'd outputs ----------------
__global__ __launch_bounds__(128) void attn_kernel(const float* __restrict__ rowmean,
                                                   const float* __restrict__ colmean,
                                                   const float* __restrict__ pos_rq, const float* __restrict__ pos_rk,
                                                   const float* __restrict__ pos_cq, const float* __restrict__ pos_ck,
                                                   float* __restrict__ xr_act, float* __restrict__ xc_act) {
    __shared__ float qr[8][128], kr[8][128], vr[16][128];
    int iscol = blockIdx.x >> 6;
    int sub = blockIdx.x & 63;
    int b = sub >> 3, head = sub & 7;
    const float* meanbuf = iscol ? colmean : rowmean;
    const float* posq = iscol ? pos_cq : pos_rq;
    const float* posk = iscol ? pos_ck : pos_rk;
    float* xact = iscol ? xc_act : xr_act;
    int i = threadIdx.x;
    float src = (i + 0.5f) * 0.125f - 0.5f;
    src = fmaxf(src, 0.f);
    int i0 = (int)src;
    if (i0 > 15) i0 = 15;
    float f = src - (float)i0;
    int i1 = (i0 + 1 > 15) ? 15 : i0 + 1;
    const float* mb = meanbuf + (size_t)b * 256 * 128;
    for (int kd = 0; kd < 8; ++kd) {
        int cq = head * 8 + kd;
        qr[kd][i] = mb[cq * 128 + i] + posq[cq * 16 + i0] * (1.f - f) + posq[cq * 16 + i1] * f;
        kr[kd][i] = mb[(64 + cq) * 128 + i] + posk[cq * 16 + i0] * (1.f - f) + posk[cq * 16 + i1] * f;
    }
    for (int d = 0; d < 16; ++d)
        vr[d][i] = mb[(128 + head * 16 + d) * 128 + i];
    __syncthreads();
    float qreg[8];
    #pragma unroll
    for (int kd = 0; kd < 8; ++kd) qreg[kd] = qr[kd][i];
    const float scale = 0.35355339059327373f;
    float m = -INFINITY;
    for (int j = 0; j < 128; ++j) {
        float sj = 0.f;
        #pragma unroll
        for (int kd = 0; kd < 8; ++kd) sj += qreg[kd] * kr[kd][j];
        m = fmaxf(m, sj * scale);
    }
    float denom = 0.f;
    float acc[16];
    #pragma unroll
    for (int d = 0; d < 16; ++d) acc[d] = 0.f;
    for (int j = 0; j < 128; ++j) {
        float sj = 0.f;
        #pragma unroll
        for (int kd = 0; kd < 8; ++kd) sj += qreg[kd] * kr[kd][j];
        float pj = __expf(sj * scale - m);
        denom += pj;
        #pragma unroll
        for (int d = 0; d < 16; ++d) acc[d] += pj * vr[d][j];
    }
    float inv = __builtin_amdgcn_rcpf(denom);
    float* xp = xact + ((size_t)b * 128 + head * 16) * 128;
    for (int d = 0; d < 16; ++d)
        xp[d * 128 + i] = fmaxf(acc[d] * inv, 0.f);
}

// ---------------- 1x1 conv on xr/xc + BN -> TRANSPOSED [b][i][ic] outputs ----------------
__global__ __launch_bounds__(256) void rc_conv_kernel(const float* __restrict__ xr_act, const float* __restrict__ xc_act,
                                                      const float* __restrict__ wrowT, const float* __restrict__ wcolT,
                                                      const float* __restrict__ rs, const float* __restrict__ rb,
                                                      const float* __restrict__ cs, const float* __restrict__ cb,
                                                      float* __restrict__ xrT, float* __restrict__ xcT) {
    __shared__ float4 lds[128][16];
    int blk = blockIdx.x;             // 0..31
    int iscol = blk >> 4;
    int rem = blk & 15;
    int b = rem >> 1;
    int i0 = (rem & 1) * 64;
    const float* src = iscol ? xc_act : xr_act;
    const float* wT  = iscol ? wcolT : wrowT;
    const float* ss  = iscol ? cs : rs;
    const float* sb  = iscol ? cb : rb;
    float* dst       = iscol ? xcT : xrT;
    int tid = threadIdx.x;
    const float4* src4 = (const float4*)(src + (size_t)b * 16384 + i0);
    for (int idx = tid; idx < 128 * 16; idx += 256) {
        int ic = idx >> 4, q = idx & 15;
        lds[ic][q] = src4[ic * 32 + q];
    }
    __syncthreads();
    int oc = tid & 127, sub = tid >> 7;
    float4 acc[8];
    #pragma unroll
    for (int q = 0; q < 8; ++q) acc[q] = make_float4(0.f, 0.f, 0.f, 0.f);
    for (int ic = 0; ic < 128; ++ic) {
        float w = wT[ic * 128 + oc];
        #pragma unroll
        for (int q = 0; q < 8; ++q) {
            float4 v = lds[ic][sub * 8 + q];
            acc[q].x += w * v.x; acc[q].y += w * v.y;
            acc[q].z += w * v.z; acc[q].w += w * v.w;
        }
    }
    float s = ss[oc], bb = sb[oc];
    int ibase = i0 + sub * 32;
    #pragma unroll
    for (int q = 0; q < 8; ++q) {
        float vv[4] = {acc[q].x, acc[q].y, acc[q].z, acc[q].w};
        #pragma unroll
        for (int r = 0; r < 4; ++r) {
            int i = ibase + q * 4 + r;
            dst[((size_t)b * 128 + i) * 128 + oc] = vv[r] * s + bb;
        }
    }
}

// ---------------- final: xx=v+xr+xc, relu, proj fp16 MFMA + BN, hsig*qkv_b -> out NCHW ----------------
__global__ __launch_bounds__(512) void final_mfma(const short* __restrict__ qh,
                                                  const float* __restrict__ xrT, const float* __restrict__ xcT,
                                                  const short* __restrict__ wproj_h,
                                                  const float* __restrict__ ps, const float* __restrict__ pb,
                                                  const float* __restrict__ qb, float* __restrict__ out) {
    __shared__ char sm[34816];
    short* ap = (short*)sm;               // [128][136] fp16
    int flat = blockIdx.x;
    int b = flat & 7, h = flat >> 3;
    int tid = threadIdx.x, lane = tid & 63, wid = tid >> 6;
    int wr = wid >> 2, wc = wid & 3;      // px half / oc quarter (32 oc)
    int l15 = lane & 15, l4 = lane >> 4;
    int spb = wr * 64 + l15;
    int ocb = wc * 32 + l15;
    for (int i = 0; i < 4; ++i) {
        int idx = tid + i * 512;          // 2048 = 128px x 16 groups
        int px = idx >> 4, g = idx & 15;
        half8 v8 = *(const half8*)(qh + ((size_t)((b * 128 + h) * 128 + px)) * 256 + 128 + g * 8);
        const float* xr = xrT + ((size_t)(b * 128 + h)) * 128 + g * 8;
        const float* xc = xcT + ((size_t)(b * 128 + px)) * 128 + g * 8;
        short8 hv;
        #pragma unroll
        for (int k = 0; k < 8; ++k) {
            float v = (float)v8[k] + xr[k] + xc[k];
            hv[k] = f2h(fmaxf(v, 0.f));
        }
        *(short8*)(ap + px * 136 + g * 8) = hv;
    }
    __syncthreads();
    f32x4 acc[4][2];
    #pragma unroll
    for (int m = 0; m < 4; ++m)
        #pragma unroll
        for (int n = 0; n < 2; ++n) acc[m][n] = (f32x4){0.f, 0.f, 0.f, 0.f};
    #pragma unroll
    for (int ks = 0; ks < 4; ++ks) {
        int ko = ks * 32 + l4 * 8;
        half8 ah[4], bh[2];
        #pragma unroll
        for (int m = 0; m < 4; ++m) ah[m] = *(const half8*)(ap + (spb + m * 16) * 136 + ko);
        #pragma unroll
        for (int n = 0; n < 2; ++n) bh[n] = *(const half8*)(wproj_h + (ocb + n * 16) * 128 + ko);
        #pragma unroll
        for (int m = 0; m < 4; ++m)
            #pragma unroll
            for (int n = 0; n < 2; ++n) acc[m][n] = MFMA(ah[m], bh[n], acc[m][n]);
    }
    float s4[2], b4[2];
    #pragma unroll
    for (int n = 0; n < 2; ++n) {
        s4[n] = ps[wc * 32 + n * 16 + l15];
        b4[n] = pb[wc * 32 + n * 16 + l15];
    }
    float* tr = (float*)sm;    // [64 ocl][129 px]
    #pragma unroll 1
    for (int p = 0; p < 2; ++p) {
        __syncthreads();
        if ((wc >> 1) == p) {
            #pragma unroll
            for (int n = 0; n < 2; ++n)
                #pragma unroll
                for (int m = 0; m < 4; ++m)
                    #pragma unroll
                    for (int r = 0; r < 4; ++r) {
                        int px = wr * 64 + m * 16 + l4 * 4 + r;
                        int ocl = (wc & 1) * 32 + n * 16 + l15;    // 0..63 within half
                        int oc = p * 64 + ocl;
                        float val = acc[m][n][r] * s4[n] + b4[n];
                        float hs = fminf(fmaxf(val + 3.f, 0.f), 6.f) * (1.f / 6.f);
                        float g = qb[((size_t)((b * 128 + h) * 128 + px)) * 128 + oc];
                        tr[ocl * 129 + px] = hs * g;
                    }
        }
        __syncthreads();
        int ocl = tid >> 3, q = tid & 7;      // 64 ocl x 8 q
        int oc = p * 64 + ocl;
        float* yp = out + (size_t)(b * 128 + oc) * S + h * 128 + q * 16;
        #pragma unroll
        for (int j = 0; j < 16; j += 4) {
            float4 v;
            v.x = tr[ocl * 129 + q * 16 + j];
            v.y = tr[ocl * 129 + q * 16 + j + 1];
            v.z = tr[ocl * 129 + q * 16 + j + 2];
            v.w = tr[ocl * 129 + q * 16 + j + 3];
            *(float4*)(yp + j) = v;
        }
    }
}

extern "C" void kernel_launch(void* const* d_in, const int* in_sizes, int n_in,
                              void* d_out, int out_size, void* d_ws, size_t ws_size,
                              hipStream_t stream) {
    const float* x       = (const float*)d_in[0];
    const float* bn1_s   = (const float*)d_in[1];
    const float* bn1_b   = (const float*)d_in[2];
    const float* fc1_w   = (const float*)d_in[3];
    const float* fc1_b   = (const float*)d_in[4];
    const float* wq      = (const float*)d_in[5];
    const float* bnq_s   = (const float*)d_in[6];
    const float* bnq_b   = (const float*)d_in[7];
    const float* wk      = (const float*)d_in[8];
    const float* bnk_s   = (const float*)d_in[9];
    const float* bnk_b   = (const float*)d_in[10];
    const float* wv      = (const float*)d_in[11];
    const float* bnv_s   = (const float*)d_in[12];
    const float* bnv_b   = (const float*)d_in[13];
    const float* pos_rq  = (const float*)d_in[14];
    const float* pos_rk  = (const float*)d_in[15];
    const float* pos_cq  = (const float*)d_in[16];
    const float* pos_ck  = (const float*)d_in[17];
    const float* wrow    = (const float*)d_in[18];
    const float* bnrow_s = (const float*)d_in[19];
    const float* bnrow_b = (const float*)d_in[20];
    const float* wcol    = (const float*)d_in[21];
    const float* bncol_s = (const float*)d_in[22];
    const float* bncol_b = (const float*)d_in[23];
    const float* wproj   = (const float*)d_in[24];
    const float* bnproj_s= (const float*)d_in[25];
    const float* bnproj_b= (const float*)d_in[26];
    const float* wdw     = (const float*)d_in[27];
    const float* bndw_s  = (const float*)d_in[28];
    const float* bndw_b  = (const float*)d_in[29];
    const float* wpw     = (const float*)d_in[30];
    const float* bnpw_s  = (const float*)d_in[31];
    const float* bnpw_b  = (const float*)d_in[32];

    char* ws = (char*)d_ws;
    short* t0p   = (short*)(ws);                        // 34,611,200  [8][130][130][128] fp16
    short* qkvh  = (short*)(ws + (size_t)136331264);    // 67,108,864  [8][128][128][256] fp16
    float* qkvb  = (float*)(ws + (size_t)270548992);    // 67,108,864  [8][128][128][128] f32
    char* sp = ws + (size_t)337657856;
    float* rowmean = (float*)sp; sp += 1048576;
    float* colmean = (float*)sp; sp += 1048576;
    float* xr_act  = (float*)sp; sp += 524288;
    float* xc_act  = (float*)sp; sp += 524288;
    float* xrT     = (float*)sp; sp += 524288;
    float* xcT     = (float*)sp; sp += 524288;
    short* wch     = (short*)sp; sp += 294912;
    short* wqkv_h  = (short*)sp; sp += 65536;
    short* wpw_h   = (short*)sp; sp += 65536;
    short* wproj_h = (short*)sp; sp += 32768;
    float* wrowT   = (float*)sp; sp += 65536;
    float* wcolT   = (float*)sp; sp += 65536;
    float* sqkv    = (float*)sp; sp += 1024;
    float* bqkv    = (float*)sp; sp += 1024;
    float* wdwT    = (float*)sp; sp += 9216;

    float* out = (float*)d_out;

    prep_kernel<<<576, 256, 0, stream>>>(wq, wk, wv, bnq_s, bnq_b, bnk_s, bnk_b, bnv_s, bnv_b,
                                         wpw, wproj, wrow, wcol, fc1_w, wdw,
                                         wqkv_h, sqkv, bqkv, wpw_h,
                                         wproj_h, wrowT, wcolT, wch, wdwT,
                                         t0p);
    pool_kernel<<<dim3(256, 8), 256, 0, stream>>>(x, bn1_s, bn1_b, t0p);
    convqkv_mfma<<<1024, 512, 0, stream>>>(t0p, wch, fc1_b,
                                           wqkv_h, sqkv, bqkv, qkvh, rowmean);
    colmean_kernel<<<1024, 256, 0, stream>>>(qkvh, colmean);
    dwpw_mfma<<<1024, 512, 0, stream>>>(qkvh, wdwT, bndw_s, bndw_b,
                                        wpw_h, bnpw_s, bnpw_b, qkvb);
    attn_kernel<<<128, 128, 0, stream>>>(rowmean, colmean, pos_rq, pos_rk, pos_cq, pos_ck,
                                         xr_act, xc_act);
    rc_conv_kernel<<<32, 256, 0, stream>>>(xr_act, xc_act, wrowT, wcolT,
                                           bnrow_s, bnrow_b, bncol_s, bncol_b, xrT, xcT);
    final_mfma<<<1024, 512, 0, stream>>>(qkvh, xrT, xcT, wproj_h,
                                         bnproj_s, bnproj_b, qkvb, out);
}

// Round 23
// 381.224 us; speedup vs baseline: 1.2813x; 1.0262x over previous
//
#include <hip/hip_runtime.h>
#include <math.h>

#define S 16384      // 128*128 spatial
#define HW 128

typedef __attribute__((ext_vector_type(8))) short short8;
typedef __attribute__((ext_vector_type(8))) _Float16 half8;
typedef __attribute__((ext_vector_type(4))) float f32x4;

__device__ __forceinline__ float mishf(float t) {
    float sp = (t > 20.0f) ? t : __logf(1.0f + __expf(t));
    float e2 = __expf(-2.0f * sp);
    return t * (1.0f - e2) * __builtin_amdgcn_rcpf(1.0f + e2);
}
__device__ __forceinline__ short f2h(float f) {   // RNE f32 -> fp16 bits
    _Float16 h = (_Float16)f;
    return __builtin_bit_cast(short, h);
}
__device__ __forceinline__ float h2f(short s) {
    return (float)__builtin_bit_cast(_Float16, s);
}
__device__ __forceinline__ void gl_lds16(const void* g, void* l) {
    __builtin_amdgcn_global_load_lds(
        (const __attribute__((address_space(1))) unsigned int*)g,
        (__attribute__((address_space(3))) unsigned int*)l, 16, 0, 0);
}
// swizzled LDS fragment read for [px][256B] rows
__device__ __forceinline__ half8 lds_fragh(const char* base, int a) {
    int p = a ^ (((a >> 8) & 7) << 4);
    return *(const half8*)(base + p);
}
// swizzled LDS fragment read for [px][128B] rows
__device__ __forceinline__ half8 lds_frag128h(const char* base, int a) {
    int p = a ^ (((a >> 7) & 7) << 4);
    return *(const half8*)(base + p);
}
__device__ __forceinline__ int swz128(int a) { return a ^ (((a >> 7) & 7) << 4); }
#define MFMA(a, b, c) __builtin_amdgcn_mfma_f32_16x16x32_f16(a, b, c, 0, 0, 0)

// ---------------- prep: fp16 weights + zero t0p borders ----------------
__global__ void prep_kernel(const float* __restrict__ wq, const float* __restrict__ wk, const float* __restrict__ wv,
                            const float* __restrict__ bnq_s, const float* __restrict__ bnq_b,
                            const float* __restrict__ bnk_s, const float* __restrict__ bnk_b,
                            const float* __restrict__ bnv_s, const float* __restrict__ bnv_b,
                            const float* __restrict__ wpw, const float* __restrict__ wproj,
                            const float* __restrict__ wrow, const float* __restrict__ wcol,
                            const float* __restrict__ fc1_w, const float* __restrict__ wdw,
                            short* __restrict__ wqkv_h,
                            float* __restrict__ sqkv, float* __restrict__ bqkv,
                            short* __restrict__ wpw_h,
                            short* __restrict__ wproj_h,
                            float* __restrict__ wrowT, float* __restrict__ wcolT,
                            short* __restrict__ wch,
                            float* __restrict__ wdwT,
                            short* __restrict__ t0p) {
    int tid = blockIdx.x * 256 + threadIdx.x;
    if (tid < 256 * 128) {            // wqkv [oc 256][ic 128] fp16
        int oc = tid >> 7, ic = tid & 127;
        float w = (oc < 64) ? wq[oc * 128 + ic]
                : (oc < 128) ? wk[(oc - 64) * 128 + ic]
                : wv[(oc - 128) * 128 + ic];
        wqkv_h[tid] = f2h(w);
    }
    if (tid < 256) {
        sqkv[tid] = (tid < 64) ? bnq_s[tid] : (tid < 128) ? bnk_s[tid - 64] : bnv_s[tid - 128];
        bqkv[tid] = (tid < 64) ? bnq_b[tid] : (tid < 128) ? bnk_b[tid - 64] : bnv_b[tid - 128];
    }
    if (tid < 128 * 256) {            // wpw [oc 128][ic 256] fp16
        wpw_h[tid] = f2h(wpw[tid]);
    }
    if (tid < 128 * 128) {
        wproj_h[tid] = f2h(wproj[tid]);   // [oc][ic]
        int ic = tid >> 7, oc = tid & 127;
        wrowT[tid] = wrow[oc * 128 + ic];
        wcolT[tid] = wcol[oc * 128 + ic];
    }
    if (tid < 9 * 128 * 128) {        // conv3x3 [tap][oc][ic] fp16
        int tap = tid >> 14;
        int oc = (tid >> 7) & 127;
        int ic = tid & 127;
        wch[tid] = f2h(fc1_w[(oc * 128 + ic) * 9 + tap]);
    }
    if (tid < 9 * 256) {              // depthwise [tap][c]
        int tap = tid / 256, c = tid % 256;
        wdwT[tap * 256 + c] = wdw[c * 9 + tap];
    }
    if (tid < 66048) {                // border zero (single plane)
        int bb = tid / 8256;
        int e = tid - bb * 8256;
        size_t ib = (size_t)bb * 130 * 130 * 128;
        short8 z = (short8){0, 0, 0, 0, 0, 0, 0, 0};
        if (e < 4160) {
            int row = (e < 2080) ? 0 : 129;
            int off = (e % 2080) * 8;
            *(short8*)(t0p + ib + (size_t)row * 130 * 128 + off) = z;
        } else {
            int e2 = e - 4160;
            int row = 1 + (e2 >> 5);
            int side = (e2 >> 4) & 1;
            int off = (e2 & 15) * 8;
            *(short8*)(t0p + ib + ((size_t)row * 130 + (side ? 129 : 0)) * 128 + off) = z;
        }
    }
}

// ---------------- pool (avg+max) + BN + Mish -> padded NHWC fp16 ----------------
__global__ __launch_bounds__(256) void pool_kernel(const float* __restrict__ x,
                                                   const float* __restrict__ s1, const float* __restrict__ b1,
                                                   short* __restrict__ t0p) {
    __shared__ short ot[64][136];
    int bx = blockIdx.x;               // 0..255
    int b = blockIdx.y;
    int h = bx >> 1, wh = bx & 1;
    int t = threadIdx.x;
    int wp = t & 31;                   // w-pair index (2 outputs each)
    int c8 = t >> 5;                   // 0..7
    int w0 = wh * 64 + wp * 2;
    for (int cs = 0; cs < 8; ++cs) {
        int c = cs * 8 + c8;           // 0..63
        const float* xp = x + (size_t)(b * 64 + c) * 65536;
        float vs[3][5], vm[3][5];
        #pragma unroll
        for (int kh = 0; kh < 3; ++kh) {
            int ih = 2 * h + kh - 1;
            bool hok = (unsigned)ih < 256u;
            #pragma unroll
            for (int j = 0; j < 5; ++j) {
                int iw = 2 * w0 - 1 + j;
                bool ok = hok && (unsigned)iw < 256u;
                float v = ok ? xp[ih * 256 + iw] : 0.f;
                vs[kh][j] = ok ? v : 0.f;
                vm[kh][j] = ok ? v : -INFINITY;
            }
        }
        #pragma unroll
        for (int o = 0; o < 2; ++o) {
            float sum = 0.f, mx = -INFINITY;
            #pragma unroll
            for (int kh = 0; kh < 3; ++kh)
                #pragma unroll
                for (int kw = 0; kw < 3; ++kw) {
                    sum += vs[kh][kw + 2 * o];
                    mx = fmaxf(mx, vm[kh][kw + 2 * o]);
                }
            float ta = mishf((sum * (1.f / 9.f)) * s1[c] + b1[c]);
            float tm = mishf(mx * s1[64 + c] + b1[64 + c]);
            ot[wp * 2 + o][c] = f2h(ta);
            ot[wp * 2 + o][64 + c] = f2h(tm);
        }
    }
    __syncthreads();
    size_t rowbase = ((size_t)(b * 130 + h + 1) * 130 + 1 + wh * 64) * 128;
    short* op = t0p + rowbase;
    for (int idx = t; idx < 64 * 16; idx += 256) {
        int wloc = idx >> 4, co = idx & 15;
        short8 v = *(const short8*)(&ot[wloc][co * 8]);
        *(short8*)(op + wloc * 128 + co * 8) = v;
    }
}

// ---------------- FUSED conv3x3 + qkv 1x1, 512 threads / 8 waves, fp16 single-term ----------------
// LDS: staging [33280] reused as A-pack [128][132] fp16; rsum f32[512] at 33792.
__global__ __launch_bounds__(512) void convqkv_mfma(const short* __restrict__ t0p,
                                                    const short* __restrict__ wch,
                                                    const float* __restrict__ fb,
                                                    const short* __restrict__ wqkv_h,
                                                    const float* __restrict__ sc, const float* __restrict__ bi,
                                                    short* __restrict__ qh, float* __restrict__ rowmean) {
    __shared__ char sm[35840];
    float* rsum = (float*)(sm + 33792);
    int flat = blockIdx.x;              // 1024
    int b = flat & 7;                   // XCD-affine
    int h = flat >> 3;
    int tid = threadIdx.x, lane = tid & 63, wid = tid >> 6;
    int l15 = lane & 15, l4 = lane >> 4;
    int wrc = wid >> 2;                 // conv px half
    int wcc = wid & 3;                  // conv oc quarter (32 oc)
    int spbc = wrc * 64 + l15;
    int ocbc = wcc * 32 + l15;
    f32x4 acc[4][2];
    #pragma unroll
    for (int m = 0; m < 4; ++m)
        #pragma unroll
        for (int n = 0; n < 2; ++n) acc[m][n] = (f32x4){0.f, 0.f, 0.f, 0.f};
    for (int kh = 0; kh < 3; ++kh) {
        __syncthreads();
        const char* gp = (const char*)(t0p + ((size_t)(b * 130 + h + kh) * 130) * 128);
        #pragma unroll
        for (int it = 0; it < 5; ++it) {
            int idx = it * 512 + tid;           // 2080 x 16B
            if (idx < 2080) {
                int dl = idx * 16;
                int srcoff = dl ^ (((dl >> 8) & 7) << 4);
                gl_lds16(gp + srcoff, sm + dl);
            }
        }
        __syncthreads();
        #pragma unroll
        for (int kw = 0; kw < 3; ++kw) {
            const short* wbh = wch + (size_t)(kh * 3 + kw) * 16384;
            #pragma unroll
            for (int ks = 0; ks < 4; ++ks) {
                int kb = ks * 64 + l4 * 16;
                int kws = ks * 32 + l4 * 8;
                half8 ah[4], bh[2];
                #pragma unroll
                for (int m = 0; m < 4; ++m)
                    ah[m] = lds_fragh(sm, ((spbc + m * 16 + kw) << 8) + kb);
                #pragma unroll
                for (int n = 0; n < 2; ++n)
                    bh[n] = *(const half8*)(wbh + (ocbc + n * 16) * 128 + kws);
                #pragma unroll
                for (int m = 0; m < 4; ++m)
                    #pragma unroll
                    for (int n = 0; n < 2; ++n)
                        acc[m][n] = MFMA(ah[m], bh[n], acc[m][n]);
            }
        }
    }
    // pack conv output (y row) + bias into fp16 A tile in LDS (reuse staging region)
    float fbv[2];
    #pragma unroll
    for (int n = 0; n < 2; ++n) fbv[n] = fb[wcc * 32 + n * 16 + l15];
    rsum[tid] = 0.f;                    // 512 entries
    __syncthreads();
    short* ap = (short*)sm;             // [128][132]
    #pragma unroll
    for (int m = 0; m < 4; ++m)
        #pragma unroll
        for (int n = 0; n < 2; ++n)
            #pragma unroll
            for (int r = 0; r < 4; ++r) {
                int px = wrc * 64 + m * 16 + l4 * 4 + r;
                int ocl = wcc * 32 + n * 16 + l15;
                ap[px * 132 + ocl] = f2h(acc[m][n][r] + fbv[n]);
            }
    __syncthreads();
    // qkv GEMM: A[128px][128ic] (LDS fp16) x B[256oc][128ic] fp16, 8 waves
    int spbq = wrc * 64 + l15;          // px half
    int ocbq = wcc * 64 + l15;          // oc quarter of 256 (64 oc)
    f32x4 aq[4][4];
    #pragma unroll
    for (int m = 0; m < 4; ++m)
        #pragma unroll
        for (int n = 0; n < 4; ++n) aq[m][n] = (f32x4){0.f, 0.f, 0.f, 0.f};
    #pragma unroll
    for (int ks = 0; ks < 4; ++ks) {
        int k0 = ks * 32 + l4 * 8;
        half8 ah[4], bh[4];
        #pragma unroll
        for (int m = 0; m < 4; ++m) ah[m] = *(const half8*)(ap + (spbq + m * 16) * 132 + k0);
        #pragma unroll
        for (int n = 0; n < 4; ++n) bh[n] = *(const half8*)(wqkv_h + (size_t)(ocbq + n * 16) * 128 + k0);
        #pragma unroll
        for (int m = 0; m < 4; ++m)
            #pragma unroll
            for (int n = 0; n < 4; ++n) aq[m][n] = MFMA(ah[m], bh[n], aq[m][n]);
    }
    // rowsum partials (raw acc; scale/bias at final store)
    #pragma unroll
    for (int n = 0; n < 4; ++n) {
        float v = 0.f;
        #pragma unroll
        for (int m = 0; m < 4; ++m)
            #pragma unroll
            for (int r = 0; r < 4; ++r) v += aq[m][n][r];
        v += __shfl_xor(v, 16);
        v += __shfl_xor(v, 32);
        if (l4 == 0) rsum[wrc * 256 + wcc * 64 + n * 16 + l15] = v;
    }
    // BN + fp16 store
    float s4[4], b4[4];
    #pragma unroll
    for (int n = 0; n < 4; ++n) {
        s4[n] = sc[wcc * 64 + n * 16 + l15];
        b4[n] = bi[wcc * 64 + n * 16 + l15];
    }
    short* rowout = qh + ((size_t)(b * 128 + h) * 128) * 256;
    #pragma unroll
    for (int m = 0; m < 4; ++m)
        #pragma unroll
        for (int n = 0; n < 4; ++n)
            #pragma unroll
            for (int r = 0; r < 4; ++r) {
                int px = wrc * 64 + m * 16 + l4 * 4 + r;
                int oc = wcc * 64 + n * 16 + l15;
                rowout[px * 256 + oc] = f2h(aq[m][n][r] * s4[n] + b4[n]);
            }
    __syncthreads();
    if (tid < 256)
        rowmean[((size_t)b * 256 + tid) * 128 + h] =
            (rsum[tid] + rsum[256 + tid]) * sc[tid] * (1.f / 128.f) + bi[tid];
}

// ---------------- colmean: mean over h of qkv fp16 NHWC ----------------
__global__ __launch_bounds__(256) void colmean_kernel(const short* __restrict__ qh,
                                                      float* __restrict__ colmean) {
    __shared__ float red[8][256];
    int blk = blockIdx.x;                 // 1024
    int b = blk & 7, w = blk >> 3;        // XCD-affine
    int tid = threadIdx.x;
    int c8g = tid & 31;                   // channel group of 8
    int hs = tid >> 5;                    // 8 h-slices of 16
    float a8[8];
    #pragma unroll
    for (int k = 0; k < 8; ++k) a8[k] = 0.f;
    for (int j = 0; j < 16; ++j) {
        int h = hs * 16 + j;
        half8 v = *(const half8*)(qh + ((size_t)((b * 128 + h) * 128 + w)) * 256 + c8g * 8);
        #pragma unroll
        for (int k = 0; k < 8; ++k) a8[k] += (float)v[k];
    }
    #pragma unroll
    for (int k = 0; k < 8; ++k) red[hs][c8g * 8 + k] = a8[k];
    __syncthreads();
    int c = tid;
    float s = 0.f;
    #pragma unroll
    for (int q = 0; q < 8; ++q) s += red[q][c];
    colmean[((size_t)b * 256 + c) * 128 + w] = s * (1.f / 128.f);
}

// ---------------- fused depthwise 3x3 + BN + ReLU + pointwise 256->128 fp16 MFMA + BN ----------------
// gate output stored fp16 (halves qb traffic; gate multiplies h-sigmoid in [0,1]).
__global__ __launch_bounds__(512) void dwpw_mfma(const short* __restrict__ qh,
                                                 const float* __restrict__ wdwT,
                                                 const float* __restrict__ ds, const float* __restrict__ db,
                                                 const short* __restrict__ wpw_h,
                                                 const float* __restrict__ sc, const float* __restrict__ bi,
                                                 short* __restrict__ qb) {
    __shared__ char sm[16384];           // dw out fp16, [128w][128B] swizzled (64 c chunk)
    int flat = blockIdx.x;
    int b = flat & 7, h = flat >> 3;
    int tid = threadIdx.x, lane = tid & 63, wid = tid >> 6;
    int wr = wid >> 2, wc = wid & 3;     // px half / oc quarter (32 oc)
    int l15 = lane & 15, l4 = lane >> 4;
    int spb = wr * 64 + l15;
    int ocb = wc * 32 + l15;
    int wdw_ = tid >> 3;      // 0..63 (w base, 2 w per thread)
    int c8t = tid & 7;        // c8 group within 64-c chunk
    f32x4 acc[4][2];
    #pragma unroll
    for (int m = 0; m < 4; ++m)
        #pragma unroll
        for (int n = 0; n < 2; ++n) acc[m][n] = (f32x4){0.f, 0.f, 0.f, 0.f};

    #pragma unroll 1
    for (int kc = 0; kc < 4; ++kc) {
        __syncthreads();      // previous chunk's MFMA reads done
        int cbase = kc * 64 + c8t * 8;
        #pragma unroll 1
        for (int i = 0; i < 2; ++i) {
            int w = wdw_ * 2 + i;
            float acc8[8];
            #pragma unroll
            for (int k = 0; k < 8; ++k) acc8[k] = 0.f;
            #pragma unroll
            for (int kh = 0; kh < 3; ++kh) {
                int ih = h + kh - 1;
                if ((unsigned)ih >= 128u) continue;
                #pragma unroll
                for (int kw = 0; kw < 3; ++kw) {
                    int iw = w + kw - 1;
                    if ((unsigned)iw >= 128u) continue;
                    half8 v = *(const half8*)(qh + ((size_t)((b * 128 + ih) * 128 + iw)) * 256 + cbase);
                    const float* wp = wdwT + (kh * 3 + kw) * 256 + cbase;
                    #pragma unroll
                    for (int k = 0; k < 8; ++k)
                        acc8[k] += wp[k] * (float)v[k];
                }
            }
            short8 hv;
            #pragma unroll
            for (int k = 0; k < 8; ++k) {
                float v = fmaxf(acc8[k] * ds[cbase + k] + db[cbase + k], 0.f);
                hv[k] = f2h(v);
            }
            *(short8*)(sm + swz128(w * 128 + c8t * 16)) = hv;
        }
        __syncthreads();
        #pragma unroll
        for (int ks = 0; ks < 2; ++ks) {
            int kb = ks * 64 + l4 * 16;               // byte offset in 128B row
            int kws = kc * 64 + ks * 32 + l4 * 8;     // weight short offset (ic)
            half8 ah[4], bh[2];
            #pragma unroll
            for (int m = 0; m < 4; ++m) ah[m] = lds_frag128h(sm, (spb + m * 16) * 128 + kb);
            #pragma unroll
            for (int n = 0; n < 2; ++n) bh[n] = *(const half8*)(wpw_h + (ocb + n * 16) * 256 + kws);
            #pragma unroll
            for (int m = 0; m < 4; ++m)
                #pragma unroll
                for (int n = 0; n < 2; ++n) acc[m][n] = MFMA(ah[m], bh[n], acc[m][n]);
        }
    }
    float s4[2], b4[2];
    #pragma unroll
    for (int n = 0; n < 2; ++n) {
        s4[n] = sc[wc * 32 + n * 16 + l15];
        b4[n] = bi[wc * 32 + n * 16 + l15];
    }
    short* rowout = qb + ((size_t)(b * 128 + h) * 128) * 128;
    #pragma unroll
    for (int m = 0; m < 4; ++m)
        #pragma unroll
        for (int n = 0; n < 2; ++n)
            #pragma unroll
            for (int r = 0; r < 4; ++r) {
                int px = wr * 64 + m * 16 + l4 * 4 + r;
                int oc = wc * 32 + n * 16 + l15;
                rowout[px * 128 + oc] = f2h(acc[m][n][r] * s4[n] + b4[n]);
            }
}

// ---------------- axial attention (row AND col in one launch) -> relu'd outputs ----------------
__global__ __launch_bounds__(128) void attn_kernel(const float* __restrict__ rowmean,
                                                   const float* __restrict__ colmean,
                                                   const float* __restrict__ pos_rq, const float* __restrict__ pos_rk,
                                                   const float* __restrict__ pos_cq, const float* __restrict__ pos_ck,
                                                   float* __restrict__ xr_act, float* __restrict__ xc_act) {
    __shared__ float qr[8][128], kr[8][128], vr[16][128];
    int iscol = blockIdx.x >> 6;
    int sub = blockIdx.x & 63;
    int b = sub >> 3, head = sub & 7;
    const float* meanbuf = iscol ? colmean : rowmean;
    const float* posq = iscol ? pos_cq : pos_rq;
    const float* posk = iscol ? pos_ck : pos_rk;
    float* xact = iscol ? xc_act : xr_act;
    int i = threadIdx.x;
    float src = (i + 0.5f) * 0.125f - 0.5f;
    src = fmaxf(src, 0.f);
    int i0 = (int)src;
    if (i0 > 15) i0 = 15;
    float f = src - (float)i0;
    int i1 = (i0 + 1 > 15) ? 15 : i0 + 1;
    const float* mb = meanbuf + (size_t)b * 256 * 128;
    for (int kd = 0; kd < 8; ++kd) {
        int cq = head * 8 + kd;
        qr[kd][i] = mb[cq * 128 + i] + posq[cq * 16 + i0] * (1.f - f) + posq[cq * 16 + i1] * f;
        kr[kd][i] = mb[(64 + cq) * 128 + i] + posk[cq * 16 + i0] * (1.f - f) + posk[cq * 16 + i1] * f;
    }
    for (int d = 0; d < 16; ++d)
        vr[d][i] = mb[(128 + head * 16 + d) * 128 + i];
    __syncthreads();
    float qreg[8];
    #pragma unroll
    for (int kd = 0; kd < 8; ++kd) qreg[kd] = qr[kd][i];
    const float scale = 0.35355339059327373f;
    float m = -INFINITY;
    for (int j = 0; j < 128; ++j) {
        float sj = 0.f;
        #pragma unroll
        for (int kd = 0; kd < 8; ++kd) sj += qreg[kd] * kr[kd][j];
        m = fmaxf(m, sj * scale);
    }
    float denom = 0.f;
    float acc[16];
    #pragma unroll
    for (int d = 0; d < 16; ++d) acc[d] = 0.f;
    for (int j = 0; j < 128; ++j) {
        float sj = 0.f;
        #pragma unroll
        for (int kd = 0; kd < 8; ++kd) sj += qreg[kd] * kr[kd][j];
        float pj = __expf(sj * scale - m);
        denom += pj;
        #pragma unroll
        for (int d = 0; d < 16; ++d) acc[d] += pj * vr[d][j];
    }
    float inv = __builtin_amdgcn_rcpf(denom);
    float* xp = xact + ((size_t)b * 128 + head * 16) * 128;
    for (int d = 0; d < 16; ++d)
        xp[d * 128 + i] = fmaxf(acc[d] * inv, 0.f);
}

// ---------------- 1x1 conv on xr/xc + BN -> TRANSPOSED [b][i][ic] outputs ----------------
__global__ __launch_bounds__(256) void rc_conv_kernel(const float* __restrict__ xr_act, const float* __restrict__ xc_act,
                                                      const float* __restrict__ wrowT, const float* __restrict__ wcolT,
                                                      const float* __restrict__ rs, const float* __restrict__ rb,
                                                      const float* __restrict__ cs, const float* __restrict__ cb,
                                                      float* __restrict__ xrT, float* __restrict__ xcT) {
    __shared__ float4 lds[128][16];
    int blk = blockIdx.x;             // 0..31
    int iscol = blk >> 4;
    int rem = blk & 15;
    int b = rem >> 1;
    int i0 = (rem & 1) * 64;
    const float* src = iscol ? xc_act : xr_act;
    const float* wT  = iscol ? wcolT : wrowT;
    const float* ss  = iscol ? cs : rs;
    const float* sb  = iscol ? cb : rb;
    float* dst       = iscol ? xcT : xrT;
    int tid = threadIdx.x;
    const float4* src4 = (const float4*)(src + (size_t)b * 16384 + i0);
    for (int idx = tid; idx < 128 * 16; idx += 256) {
        int ic = idx >> 4, q = idx & 15;
        lds[ic][q] = src4[ic * 32 + q];
    }
    __syncthreads();
    int oc = tid & 127, sub = tid >> 7;
    float4 acc[8];
    #pragma unroll
    for (int q = 0; q < 8; ++q) acc[q] = make_float4(0.f, 0.f, 0.f, 0.f);
    for (int ic = 0; ic < 128; ++ic) {
        float w = wT[ic * 128 + oc];
        #pragma unroll
        for (int q = 0; q < 8; ++q) {
            float4 v = lds[ic][sub * 8 + q];
            acc[q].x += w * v.x; acc[q].y += w * v.y;
            acc[q].z += w * v.z; acc[q].w += w * v.w;
        }
    }
    float s = ss[oc], bb = sb[oc];
    int ibase = i0 + sub * 32;
    #pragma unroll
    for (int q = 0; q < 8; ++q) {
        float vv[4] = {acc[q].x, acc[q].y, acc[q].z, acc[q].w};
        #pragma unroll
        for (int r = 0; r < 4; ++r) {
            int i = ibase + q * 4 + r;
            dst[((size_t)b * 128 + i) * 128 + oc] = vv[r] * s + bb;
        }
    }
}

// ---------------- final: xx=v+xr+xc, relu, proj fp16 MFMA + BN, hsig*qkv_b -> out NCHW ----------------
__global__ __launch_bounds__(512) void final_mfma(const short* __restrict__ qh,
                                                  const float* __restrict__ xrT, const float* __restrict__ xcT,
                                                  const short* __restrict__ wproj_h,
                                                  const float* __restrict__ ps, const float* __restrict__ pb,
                                                  const short* __restrict__ qb, float* __restrict__ out) {
    __shared__ char sm[34816];
    short* ap = (short*)sm;               // [128][136] fp16
    int flat = blockIdx.x;
    int b = flat & 7, h = flat >> 3;
    int tid = threadIdx.x, lane = tid & 63, wid = tid >> 6;
    int wr = wid >> 2, wc = wid & 3;      // px half / oc quarter (32 oc)
    int l15 = lane & 15, l4 = lane >> 4;
    int spb = wr * 64 + l15;
    int ocb = wc * 32 + l15;
    for (int i = 0; i < 4; ++i) {
        int idx = tid + i * 512;          // 2048 = 128px x 16 groups
        int px = idx >> 4, g = idx & 15;
        half8 v8 = *(const half8*)(qh + ((size_t)((b * 128 + h) * 128 + px)) * 256 + 128 + g * 8);
        const float* xr = xrT + ((size_t)(b * 128 + h)) * 128 + g * 8;
        const float* xc = xcT + ((size_t)(b * 128 + px)) * 128 + g * 8;
        short8 hv;
        #pragma unroll
        for (int k = 0; k < 8; ++k) {
            float v = (float)v8[k] + xr[k] + xc[k];
            hv[k] = f2h(fmaxf(v, 0.f));
        }
        *(short8*)(ap + px * 136 + g * 8) = hv;
    }
    __syncthreads();
    f32x4 acc[4][2];
    #pragma unroll
    for (int m = 0; m < 4; ++m)
        #pragma unroll
        for (int n = 0; n < 2; ++n) acc[m][n] = (f32x4){0.f, 0.f, 0.f, 0.f};
    #pragma unroll
    for (int ks = 0; ks < 4; ++ks) {
        int ko = ks * 32 + l4 * 8;
        half8 ah[4], bh[2];
        #pragma unroll
        for (int m = 0; m < 4; ++m) ah[m] = *(const half8*)(ap + (spb + m * 16) * 136 + ko);
        #pragma unroll
        for (int n = 0; n < 2; ++n) bh[n] = *(const half8*)(wproj_h + (ocb + n * 16) * 128 + ko);
        #pragma unroll
        for (int m = 0; m < 4; ++m)
            #pragma unroll
            for (int n = 0; n < 2; ++n) acc[m][n] = MFMA(ah[m], bh[n], acc[m][n]);
    }
    float s4[2], b4[2];
    #pragma unroll
    for (int n = 0; n < 2; ++n) {
        s4[n] = ps[wc * 32 + n * 16 + l15];
        b4[n] = pb[wc * 32 + n * 16 + l15];
    }
    float* tr = (float*)sm;    // [64 ocl][129 px]
    #pragma unroll 1
    for (int p = 0; p < 2; ++p) {
        __syncthreads();
        if ((wc >> 1) == p) {
            #pragma unroll
            for (int n = 0; n < 2; ++n)
                #pragma unroll
                for (int m = 0; m < 4; ++m)
                    #pragma unroll
                    for (int r = 0; r < 4; ++r) {
                        int px = wr * 64 + m * 16 + l4 * 4 + r;
                        int ocl = (wc & 1) * 32 + n * 16 + l15;    // 0..63 within half
                        int oc = p * 64 + ocl;
                        float val = acc[m][n][r] * s4[n] + b4[n];
                        float hs = fminf(fmaxf(val + 3.f, 0.f), 6.f) * (1.f / 6.f);
                        float g = h2f(qb[((size_t)((b * 128 + h) * 128 + px)) * 128 + oc]);
                        tr[ocl * 129 + px] = hs * g;
                    }
        }
        __syncthreads();
        int ocl = tid >> 3, q = tid & 7;      // 64 ocl x 8 q
        int oc = p * 64 + ocl;
        float* yp = out + (size_t)(b * 128 + oc) * S + h * 128 + q * 16;
        #pragma unroll
        for (int j = 0; j < 16; j += 4) {
            float4 v;
            v.x = tr[ocl * 129 + q * 16 + j];
            v.y = tr[ocl * 129 + q * 16 + j + 1];
            v.z = tr[ocl * 129 + q * 16 + j + 2];
            v.w = tr[ocl * 129 + q * 16 + j + 3];
            *(float4*)(yp + j) = v;
        }
    }
}

extern "C" void kernel_launch(void* const* d_in, const int* in_sizes, int n_in,
                              void* d_out, int out_size, void* d_ws, size_t ws_size,
                              hipStream_t stream) {
    const float* x       = (const float*)d_in[0];
    const float* bn1_s   = (const float*)d_in[1];
    const float* bn1_b   = (const float*)d_in[2];
    const float* fc1_w   = (const float*)d_in[3];
    const float* fc1_b   = (const float*)d_in[4];
    const float* wq      = (const float*)d_in[5];
    const float* bnq_s   = (const float*)d_in[6];
    const float* bnq_b   = (const float*)d_in[7];
    const float* wk      = (const float*)d_in[8];
    const float* bnk_s   = (const float*)d_in[9];
    const float* bnk_b   = (const float*)d_in[10];
    const float* wv      = (const float*)d_in[11];
    const float* bnv_s   = (const float*)d_in[12];
    const float* bnv_b   = (const float*)d_in[13];
    const float* pos_rq  = (const float*)d_in[14];
    const float* pos_rk  = (const float*)d_in[15];
    const float* pos_cq  = (const float*)d_in[16];
    const float* pos_ck  = (const float*)d_in[17];
    const float* wrow    = (const float*)d_in[18];
    const float* bnrow_s = (const float*)d_in[19];
    const float* bnrow_b = (const float*)d_in[20];
    const float* wcol    = (const float*)d_in[21];
    const float* bncol_s = (const float*)d_in[22];
    const float* bncol_b = (const float*)d_in[23];
    const float* wproj   = (const float*)d_in[24];
    const float* bnproj_s= (const float*)d_in[25];
    const float* bnproj_b= (const float*)d_in[26];
    const float* wdw     = (const float*)d_in[27];
    const float* bndw_s  = (const float*)d_in[28];
    const float* bndw_b  = (const float*)d_in[29];
    const float* wpw     = (const float*)d_in[30];
    const float* bnpw_s  = (const float*)d_in[31];
    const float* bnpw_b  = (const float*)d_in[32];

    char* ws = (char*)d_ws;
    short* t0p   = (short*)(ws);                        // 34,611,200  [8][130][130][128] fp16
    short* qkvh  = (short*)(ws + (size_t)136331264);    // 67,108,864  [8][128][128][256] fp16
    short* qkvb  = (short*)(ws + (size_t)270548992);    // 33,554,432  [8][128][128][128] fp16
    char* sp = ws + (size_t)337657856;
    float* rowmean = (float*)sp; sp += 1048576;
    float* colmean = (float*)sp; sp += 1048576;
    float* xr_act  = (float*)sp; sp += 524288;
    float* xc_act  = (float*)sp; sp += 524288;
    float* xrT     = (float*)sp; sp += 524288;
    float* xcT     = (float*)sp; sp += 524288;
    short* wch     = (short*)sp; sp += 294912;
    short* wqkv_h  = (short*)sp; sp += 65536;
    short* wpw_h   = (short*)sp; sp += 65536;
    short* wproj_h = (short*)sp; sp += 32768;
    float* wrowT   = (float*)sp; sp += 65536;
    float* wcolT   = (float*)sp; sp += 65536;
    float* sqkv    = (float*)sp; sp += 1024;
    float* bqkv    = (float*)sp; sp += 1024;
    float* wdwT    = (float*)sp; sp += 9216;

    float* out = (float*)d_out;

    prep_kernel<<<576, 256, 0, stream>>>(wq, wk, wv, bnq_s, bnq_b, bnk_s, bnk_b, bnv_s, bnv_b,
                                         wpw, wproj, wrow, wcol, fc1_w, wdw,
                                         wqkv_h, sqkv, bqkv, wpw_h,
                                         wproj_h, wrowT, wcolT, wch, wdwT,
                                         t0p);
    pool_kernel<<<dim3(256, 8), 256, 0, stream>>>(x, bn1_s, bn1_b, t0p);
    convqkv_mfma<<<1024, 512, 0, stream>>>(t0p, wch, fc1_b,
                                           wqkv_h, sqkv, bqkv, qkvh, rowmean);
    colmean_kernel<<<1024, 256, 0, stream>>>(qkvh, colmean);
    dwpw_mfma<<<1024, 512, 0, stream>>>(qkvh, wdwT, bndw_s, bndw_b,
                                        wpw_h, bnpw_s, bnpw_b, qkvb);
    attn_kernel<<<128, 128, 0, stream>>>(rowmean, colmean, pos_rq, pos_rk, pos_cq, pos_ck,
                                         xr_act, xc_act);
    rc_conv_kernel<<<32, 256, 0, stream>>>(xr_act, xc_act, wrowT, wcolT,
                                           bnrow_s, bnrow_b, bncol_s, bncol_b, xrT, xcT);
    final_mfma<<<1024, 512, 0, stream>>>(qkvh, xrT, xcT, wproj_h,
                                         bnproj_s, bnproj_b, qkvb, out);
}